// Round 1
// baseline (11816.161 us; speedup 1.0000x reference)
//
#include <hip/hip_runtime.h>
#include <hip/hip_bf16.h>
#include <math.h>

#define N_NODES 100000
#define N_EDGES 3200000
#define F_IN    512
#define HIDDEN  256
#define NCLASS  40

// ---------------------------------------------------------------------------
// GEMM1: C[M,256] = A[M,512] @ B[512,256], fp32, 64x64 tile, 4x4 per thread
// ---------------------------------------------------------------------------
__global__ __launch_bounds__(256) void gemm1_kernel(const float* __restrict__ A,
                                                    const float* __restrict__ B,
                                                    float* __restrict__ C,
                                                    int M) {
    const int K = F_IN, N = HIDDEN;
    __shared__ float As[16][65];   // [k][m], padded to dodge bank conflicts
    __shared__ float Bs[16][64];   // [k][n]

    int t  = threadIdx.x;
    int m0 = blockIdx.x * 64;
    int n0 = blockIdx.y * 64;
    int tx = t & 15, ty = t >> 4;

    float acc[4][4] = {};

    for (int k0 = 0; k0 < K; k0 += 16) {
        #pragma unroll
        for (int i = 0; i < 4; i++) {
            int idx = t + i * 256;          // 0..1023
            int r = idx >> 4, c = idx & 15; // r: m-local 0..63, c: k-local 0..15
            int m = m0 + r;
            As[c][r] = (m < M) ? A[(size_t)m * K + k0 + c] : 0.f;
        }
        #pragma unroll
        for (int i = 0; i < 4; i++) {
            int idx = t + i * 256;
            int r = idx >> 6, c = idx & 63; // r: k-local, c: n-local
            Bs[r][c] = B[(size_t)(k0 + r) * N + n0 + c];
        }
        __syncthreads();
        #pragma unroll
        for (int kk = 0; kk < 16; kk++) {
            float a[4], b[4];
            #pragma unroll
            for (int i = 0; i < 4; i++) a[i] = As[kk][ty * 4 + i];
            #pragma unroll
            for (int j = 0; j < 4; j++) b[j] = Bs[kk][tx * 4 + j];
            #pragma unroll
            for (int i = 0; i < 4; i++)
                #pragma unroll
                for (int j = 0; j < 4; j++)
                    acc[i][j] += a[i] * b[j];
        }
        __syncthreads();
    }

    #pragma unroll
    for (int i = 0; i < 4; i++) {
        int m = m0 + ty * 4 + i;
        if (m < M) {
            #pragma unroll
            for (int j = 0; j < 4; j++)
                C[(size_t)m * N + n0 + tx * 4 + j] = acc[i][j];
        }
    }
}

// ---------------------------------------------------------------------------
// SpMM scatter, D=256: one wave per edge, float4 per lane (64*4 = 256)
// ---------------------------------------------------------------------------
__global__ __launch_bounds__(256) void spmm256_kernel(const int* __restrict__ erow,
                                                      const int* __restrict__ ecol,
                                                      const float* __restrict__ evals,
                                                      const float* __restrict__ H,
                                                      float* __restrict__ out,
                                                      int E) {
    int wid  = (int)((blockIdx.x * (size_t)blockDim.x + threadIdx.x) >> 6);
    int lane = threadIdx.x & 63;
    if (wid >= E) return;
    int r = erow[wid];
    int c = ecol[wid];
    float v = evals[wid];
    const float4* src = (const float4*)(H + (size_t)c * HIDDEN);
    float4 m = src[lane];
    float* dst = out + (size_t)r * HIDDEN + lane * 4;
    atomicAdd(dst + 0, v * m.x);
    atomicAdd(dst + 1, v * m.y);
    atomicAdd(dst + 2, v * m.z);
    atomicAdd(dst + 3, v * m.w);
}

// ---------------------------------------------------------------------------
// GEMM2 with fused ReLU on input: H2[M,40] = relu(A1)[M,256] @ W2[256,40]
// ---------------------------------------------------------------------------
#define G2_ROWS 32
__global__ __launch_bounds__(256) void gemm2_kernel(const float* __restrict__ A1,
                                                    const float* __restrict__ W2,
                                                    float* __restrict__ H2,
                                                    int M) {
    __shared__ float sA[G2_ROWS * HIDDEN];
    int t  = threadIdx.x;
    int m0 = blockIdx.x * G2_ROWS;

    #pragma unroll
    for (int i = 0; i < G2_ROWS * HIDDEN / 256; i++) {
        int idx = t + i * 256;
        int r = idx >> 8;          // local row
        int m = m0 + r;
        float v = (m < M) ? A1[(size_t)m * HIDDEN + (idx & 255)] : 0.f;
        sA[idx] = fmaxf(v, 0.f);
    }
    __syncthreads();

    #pragma unroll
    for (int i = 0; i < 5; i++) {
        int o = t + i * 256;            // 0..1279
        int r = o / NCLASS, n = o % NCLASS;
        float acc = 0.f;
        #pragma unroll 4
        for (int k = 0; k < HIDDEN; k++)
            acc += sA[r * HIDDEN + k] * W2[k * NCLASS + n];
        int m = m0 + r;
        if (m < M) H2[(size_t)m * NCLASS + n] = acc;
    }
}

// ---------------------------------------------------------------------------
// SpMM scatter, D=40: one wave per edge, lanes 0..39 active
// ---------------------------------------------------------------------------
__global__ __launch_bounds__(256) void spmm40_kernel(const int* __restrict__ erow,
                                                     const int* __restrict__ ecol,
                                                     const float* __restrict__ evals,
                                                     const float* __restrict__ H,
                                                     float* __restrict__ out,
                                                     int E) {
    int wid  = (int)((blockIdx.x * (size_t)blockDim.x + threadIdx.x) >> 6);
    int lane = threadIdx.x & 63;
    if (wid >= E) return;
    int r = erow[wid];
    int c = ecol[wid];
    float v = evals[wid];
    if (lane < NCLASS) {
        float x = H[(size_t)c * NCLASS + lane];
        atomicAdd(out + (size_t)r * NCLASS + lane, v * x);
    }
}

// ---------------------------------------------------------------------------
// Fused ReLU + log_softmax over 40 classes: one wave per row
// ---------------------------------------------------------------------------
__global__ __launch_bounds__(256) void logsoftmax_kernel(const float* __restrict__ A2,
                                                         float* __restrict__ out,
                                                         int M) {
    int wid  = (int)((blockIdx.x * (size_t)blockDim.x + threadIdx.x) >> 6);
    int lane = threadIdx.x & 63;
    if (wid >= M) return;

    float z = -INFINITY;
    if (lane < NCLASS) z = fmaxf(A2[(size_t)wid * NCLASS + lane], 0.f);

    float mx = z;
    #pragma unroll
    for (int off = 32; off >= 1; off >>= 1)
        mx = fmaxf(mx, __shfl_xor(mx, off));

    float e = (lane < NCLASS) ? expf(z - mx) : 0.f;
    float s = e;
    #pragma unroll
    for (int off = 32; off >= 1; off >>= 1)
        s += __shfl_xor(s, off);

    float lse = logf(s);
    if (lane < NCLASS)
        out[(size_t)wid * NCLASS + lane] = z - mx - lse;
}

// ---------------------------------------------------------------------------
extern "C" void kernel_launch(void* const* d_in, const int* in_sizes, int n_in,
                              void* d_out, int out_size, void* d_ws, size_t ws_size,
                              hipStream_t stream) {
    const float* x     = (const float*)d_in[0];
    const int*   erow  = (const int*)d_in[1];
    const int*   ecol  = (const int*)d_in[2];
    const float* evals = (const float*)d_in[3];
    const float* W1    = (const float*)d_in[4];
    const float* W2    = (const float*)d_in[5];
    float* out = (float*)d_out;

    const int M = N_NODES;
    const int E = N_EDGES;

    // workspace layout (floats):
    //   H1: [0,            25.6M)   -- 100000*256
    //   A1: [25.6M,        51.2M)
    // then (after spmm1 consumed H1):
    //   H2: [0,            4.0M)    -- 100000*40
    //   A2: [4.0M,         8.0M)
    float* H1 = (float*)d_ws;
    float* A1 = H1 + (size_t)N_NODES * HIDDEN;
    float* H2 = (float*)d_ws;
    float* A2 = H2 + (size_t)N_NODES * NCLASS;

    // zero A1 (segment_sum identity)
    hipMemsetAsync(A1, 0, (size_t)N_NODES * HIDDEN * sizeof(float), stream);

    // layer 1 projection
    dim3 g1((M + 63) / 64, HIDDEN / 64);
    gemm1_kernel<<<g1, 256, 0, stream>>>(x, W1, H1, M);

    // layer 1 aggregation (atomics into A1)
    int spmm_blocks = (E + 3) / 4;   // 4 waves per block
    spmm256_kernel<<<spmm_blocks, 256, 0, stream>>>(erow, ecol, evals, H1, A1, E);

    // layer 2 projection (relu fused on A1 read); H1 now dead, reuse region
    gemm2_kernel<<<(M + G2_ROWS - 1) / G2_ROWS, 256, 0, stream>>>(A1, W2, H2, M);

    // zero A2 (region overlapped old H1 -- safe: spmm1 already done on stream)
    hipMemsetAsync(A2, 0, (size_t)N_NODES * NCLASS * sizeof(float), stream);

    // layer 2 aggregation
    spmm40_kernel<<<spmm_blocks, 256, 0, stream>>>(erow, ecol, evals, H2, A2, E);

    // relu + log_softmax
    int ls_blocks = (M * 64 + 255) / 256;
    logsoftmax_kernel<<<ls_blocks, 256, 0, stream>>>(A2, out, M);
}

// Round 2
// 1523.615 us; speedup vs baseline: 7.7553x; 7.7553x over previous
//
#include <hip/hip_runtime.h>
#include <hip/hip_bf16.h>
#include <math.h>

#define N_NODES 100000
#define N_EDGES 3200000
#define F_IN    512
#define HIDDEN  256
#define NCLASS  40

#define SCAN_B  256
#define N_SCANB ((N_NODES + SCAN_B - 1) / SCAN_B)   // 391

// ---------------------------------------------------------------------------
// CSR build: histogram
// ---------------------------------------------------------------------------
__global__ __launch_bounds__(256) void hist_kernel(const int* __restrict__ erow,
                                                   int* __restrict__ deg, int E) {
    int e = blockIdx.x * 256 + threadIdx.x;
    if (e < E) atomicAdd(&deg[erow[e]], 1);
}

// exclusive scan, pass A: per-block scan + block sums
__global__ __launch_bounds__(256) void scanA_kernel(const int* __restrict__ deg,
                                                    int* __restrict__ rptr,
                                                    int* __restrict__ bsum, int n) {
    __shared__ int s[SCAN_B];
    int i = blockIdx.x * SCAN_B + threadIdx.x;
    int v = (i < n) ? deg[i] : 0;
    s[threadIdx.x] = v;
    __syncthreads();
    #pragma unroll
    for (int off = 1; off < SCAN_B; off <<= 1) {
        int t = (threadIdx.x >= off) ? s[threadIdx.x - off] : 0;
        __syncthreads();
        s[threadIdx.x] += t;
        __syncthreads();
    }
    if (i < n) rptr[i] = s[threadIdx.x] - v;          // exclusive
    if (threadIdx.x == SCAN_B - 1) bsum[blockIdx.x] = s[SCAN_B - 1];
}

// pass B: scan the block sums (NB=391 < 512) in one block
__global__ __launch_bounds__(512) void scanB_kernel(int* __restrict__ bsum, int nb) {
    __shared__ int s[512];
    int t = threadIdx.x;
    int v = (t < nb) ? bsum[t] : 0;
    s[t] = v;
    __syncthreads();
    #pragma unroll
    for (int off = 1; off < 512; off <<= 1) {
        int x = (t >= off) ? s[t - off] : 0;
        __syncthreads();
        s[t] += x;
        __syncthreads();
    }
    if (t < nb) bsum[t] = s[t] - v;                   // exclusive
}

// pass C: add block offsets, zero cursor, write rptr[n]=E
__global__ __launch_bounds__(256) void scanC_kernel(int* __restrict__ rptr,
                                                    const int* __restrict__ bsum,
                                                    int* __restrict__ cursor,
                                                    int n, int E) {
    int i = blockIdx.x * SCAN_B + threadIdx.x;
    if (i < n) {
        rptr[i] += bsum[blockIdx.x];
        cursor[i] = 0;
    }
    if (i == 0) rptr[n] = E;
}

// fill: permute (col, val) pairs into CSR order
__global__ __launch_bounds__(256) void fill_kernel(const int* __restrict__ erow,
                                                   const int* __restrict__ ecol,
                                                   const float* __restrict__ evals,
                                                   const int* __restrict__ rptr,
                                                   int* __restrict__ cursor,
                                                   int2* __restrict__ cv, int E) {
    int e = blockIdx.x * 256 + threadIdx.x;
    if (e < E) {
        int r = erow[e];
        int p = rptr[r] + atomicAdd(&cursor[r], 1);
        cv[p] = make_int2(ecol[e], __float_as_int(evals[e]));
    }
}

// ---------------------------------------------------------------------------
// GEMM1: C[M,256] = A[M,512] @ B[512,256], fp32, 64x64 tile, 4x4 per thread
// ---------------------------------------------------------------------------
__global__ __launch_bounds__(256) void gemm1_kernel(const float* __restrict__ A,
                                                    const float* __restrict__ B,
                                                    float* __restrict__ C,
                                                    int M) {
    const int K = F_IN, N = HIDDEN;
    __shared__ float As[16][65];
    __shared__ float Bs[16][64];

    int t  = threadIdx.x;
    int m0 = blockIdx.x * 64;
    int n0 = blockIdx.y * 64;
    int tx = t & 15, ty = t >> 4;

    float acc[4][4] = {};

    for (int k0 = 0; k0 < K; k0 += 16) {
        #pragma unroll
        for (int i = 0; i < 4; i++) {
            int idx = t + i * 256;
            int r = idx >> 4, c = idx & 15;
            int m = m0 + r;
            As[c][r] = (m < M) ? A[(size_t)m * K + k0 + c] : 0.f;
        }
        #pragma unroll
        for (int i = 0; i < 4; i++) {
            int idx = t + i * 256;
            int r = idx >> 6, c = idx & 63;
            Bs[r][c] = B[(size_t)(k0 + r) * N + n0 + c];
        }
        __syncthreads();
        #pragma unroll
        for (int kk = 0; kk < 16; kk++) {
            float a[4], b[4];
            #pragma unroll
            for (int i = 0; i < 4; i++) a[i] = As[kk][ty * 4 + i];
            #pragma unroll
            for (int j = 0; j < 4; j++) b[j] = Bs[kk][tx * 4 + j];
            #pragma unroll
            for (int i = 0; i < 4; i++)
                #pragma unroll
                for (int j = 0; j < 4; j++)
                    acc[i][j] += a[i] * b[j];
        }
        __syncthreads();
    }

    #pragma unroll
    for (int i = 0; i < 4; i++) {
        int m = m0 + ty * 4 + i;
        if (m < M) {
            #pragma unroll
            for (int j = 0; j < 4; j++)
                C[(size_t)m * N + n0 + tx * 4 + j] = acc[i][j];
        }
    }
}

// ---------------------------------------------------------------------------
// Fused SpMM(D=256, gather) + ReLU + GEMM2: H2[r,0:40] = relu(sum_e v*H1[c]) @ W2
// One wave per row; M % 4 == 0 so grid is exact (no divergent barrier).
// ---------------------------------------------------------------------------
__global__ __launch_bounds__(256) void spmm_gemm2_kernel(const int* __restrict__ rptr,
                                                         const int2* __restrict__ cv,
                                                         const float* __restrict__ H1,
                                                         const float* __restrict__ W2,
                                                         float* __restrict__ H2) {
    __shared__ float sW2[HIDDEN * NCLASS];    // 40 KB
    __shared__ float srow[4][HIDDEN];         // 4 KB

    int t = threadIdx.x;
    for (int i = t; i < HIDDEN * NCLASS; i += 256) sW2[i] = W2[i];

    int wave = t >> 6, lane = t & 63;
    int r = blockIdx.x * 4 + wave;

    int e0 = rptr[r], e1 = rptr[r + 1];
    float4 acc = {0.f, 0.f, 0.f, 0.f};

    int e = e0;
    for (; e + 1 < e1; e += 2) {
        int2 p0 = cv[e], p1 = cv[e + 1];
        float v0 = __int_as_float(p0.y), v1 = __int_as_float(p1.y);
        const float4* s0 = (const float4*)(H1 + (size_t)p0.x * HIDDEN);
        const float4* s1 = (const float4*)(H1 + (size_t)p1.x * HIDDEN);
        float4 h0 = s0[lane], h1 = s1[lane];
        acc.x += v0 * h0.x + v1 * h1.x;
        acc.y += v0 * h0.y + v1 * h1.y;
        acc.z += v0 * h0.z + v1 * h1.z;
        acc.w += v0 * h0.w + v1 * h1.w;
    }
    if (e < e1) {
        int2 p0 = cv[e];
        float v0 = __int_as_float(p0.y);
        const float4* s0 = (const float4*)(H1 + (size_t)p0.x * HIDDEN);
        float4 h0 = s0[lane];
        acc.x += v0 * h0.x;
        acc.y += v0 * h0.y;
        acc.z += v0 * h0.z;
        acc.w += v0 * h0.w;
    }

    // relu, stage row in LDS
    acc.x = fmaxf(acc.x, 0.f); acc.y = fmaxf(acc.y, 0.f);
    acc.z = fmaxf(acc.z, 0.f); acc.w = fmaxf(acc.w, 0.f);
    ((float4*)srow[wave])[lane] = acc;
    __syncthreads();   // uniform: grid covers rows exactly

    if (lane < NCLASS) {
        float o = 0.f;
        #pragma unroll 8
        for (int k = 0; k < HIDDEN; k++)
            o = fmaf(srow[wave][k], sW2[k * NCLASS + lane], o);
        H2[(size_t)r * NCLASS + lane] = o;
    }
}

// ---------------------------------------------------------------------------
// Fused SpMM(D=40, gather) + ReLU + log_softmax. One wave per row.
// ---------------------------------------------------------------------------
__global__ __launch_bounds__(256) void spmm40_ls_kernel(const int* __restrict__ rptr,
                                                        const int2* __restrict__ cv,
                                                        const float* __restrict__ H2,
                                                        float* __restrict__ out) {
    int t = threadIdx.x;
    int wave = t >> 6, lane = t & 63;
    int r = blockIdx.x * 4 + wave;

    int e0 = rptr[r], e1 = rptr[r + 1];
    float acc = 0.f;

    int e = e0;
    for (; e + 1 < e1; e += 2) {
        int2 p0 = cv[e], p1 = cv[e + 1];
        float v0 = __int_as_float(p0.y), v1 = __int_as_float(p1.y);
        float x0 = 0.f, x1 = 0.f;
        if (lane < NCLASS) {
            x0 = H2[(size_t)p0.x * NCLASS + lane];
            x1 = H2[(size_t)p1.x * NCLASS + lane];
        }
        acc += v0 * x0 + v1 * x1;
    }
    if (e < e1) {
        int2 p0 = cv[e];
        float v0 = __int_as_float(p0.y);
        if (lane < NCLASS) acc += v0 * H2[(size_t)p0.x * NCLASS + lane];
    }

    float z = (lane < NCLASS) ? fmaxf(acc, 0.f) : -INFINITY;
    float mx = z;
    #pragma unroll
    for (int off = 32; off >= 1; off >>= 1)
        mx = fmaxf(mx, __shfl_xor(mx, off));

    float ee = (lane < NCLASS) ? expf(z - mx) : 0.f;
    float s = ee;
    #pragma unroll
    for (int off = 32; off >= 1; off >>= 1)
        s += __shfl_xor(s, off);

    float lse = logf(s);
    if (lane < NCLASS)
        out[(size_t)r * NCLASS + lane] = z - mx - lse;
}

// ---------------------------------------------------------------------------
extern "C" void kernel_launch(void* const* d_in, const int* in_sizes, int n_in,
                              void* d_out, int out_size, void* d_ws, size_t ws_size,
                              hipStream_t stream) {
    const float* x     = (const float*)d_in[0];
    const int*   erow  = (const int*)d_in[1];
    const int*   ecol  = (const int*)d_in[2];
    const float* evals = (const float*)d_in[3];
    const float* W1    = (const float*)d_in[4];
    const float* W2    = (const float*)d_in[5];
    float* out = (float*)d_out;

    const int M = N_NODES;
    const int E = N_EDGES;

    // workspace layout (all offsets 256B-aligned):
    //   deg/cursor : 100000 ints      (400,000 B)
    //   rptr       : 100001 ints      (400,004 B)
    //   bsum       : 512 ints
    //   cv         : 3.2M int2        (25.6 MB)
    //   H1         : 100000*256 f32   (102.4 MB)
    //   H2         : 100000*40 f32    (16 MB)
    // total ~145 MB
    char* p = (char*)d_ws;
    auto alloc = [&](size_t bytes) {
        char* q = p;
        p += (bytes + 255) & ~(size_t)255;
        return q;
    };
    int*   deg  = (int*)alloc(sizeof(int) * N_NODES);        // doubles as cursor
    int*   rptr = (int*)alloc(sizeof(int) * (N_NODES + 1));
    int*   bsum = (int*)alloc(sizeof(int) * 512);
    int2*  cv   = (int2*)alloc(sizeof(int2) * N_EDGES);
    float* H1   = (float*)alloc(sizeof(float) * (size_t)N_NODES * HIDDEN);
    float* H2   = (float*)alloc(sizeof(float) * (size_t)N_NODES * NCLASS);

    // --- CSR build ---
    hipMemsetAsync(deg, 0, sizeof(int) * N_NODES, stream);
    hist_kernel<<<E / 256, 256, 0, stream>>>(erow, deg, E);
    scanA_kernel<<<N_SCANB, SCAN_B, 0, stream>>>(deg, rptr, bsum, N_NODES);
    scanB_kernel<<<1, 512, 0, stream>>>(bsum, N_SCANB);
    scanC_kernel<<<N_SCANB, SCAN_B, 0, stream>>>(rptr, bsum, deg, N_NODES, E);
    fill_kernel<<<E / 256, 256, 0, stream>>>(erow, ecol, evals, rptr, deg, cv, E);

    // --- layer 1 projection ---
    dim3 g1((M + 63) / 64, HIDDEN / 64);
    gemm1_kernel<<<g1, 256, 0, stream>>>(x, W1, H1, M);

    // --- fused: aggregate(H1) + relu + @W2 ---
    spmm_gemm2_kernel<<<M / 4, 256, 0, stream>>>(rptr, cv, H1, W2, H2);

    // --- fused: aggregate(H2) + relu + log_softmax ---
    spmm40_ls_kernel<<<M / 4, 256, 0, stream>>>(rptr, cv, H2, out);
}

// Round 3
// 971.145 us; speedup vs baseline: 12.1673x; 1.5689x over previous
//
#include <hip/hip_runtime.h>
#include <math.h>

#define N_NODES 100000
#define N_EDGES 3200000
#define F_IN    512
#define HIDDEN  256
#define NCLASS  40

#define SCAN_B  256
#define N_SCANB ((N_NODES + SCAN_B - 1) / SCAN_B)   // 391

typedef __attribute__((ext_vector_type(8))) _Float16 half8;
typedef __attribute__((ext_vector_type(4))) _Float16 half4;
typedef __attribute__((ext_vector_type(4))) float    f32x4;

// ---------------------------------------------------------------------------
// CSR build
// ---------------------------------------------------------------------------
__global__ __launch_bounds__(256) void hist_kernel(const int* __restrict__ erow,
                                                   int* __restrict__ deg, int E) {
    int e = blockIdx.x * 256 + threadIdx.x;
    if (e < E) atomicAdd(&deg[erow[e]], 1);
}

__global__ __launch_bounds__(256) void scanA_kernel(const int* __restrict__ deg,
                                                    int* __restrict__ rptr,
                                                    int* __restrict__ bsum, int n) {
    __shared__ int s[SCAN_B];
    int i = blockIdx.x * SCAN_B + threadIdx.x;
    int v = (i < n) ? deg[i] : 0;
    s[threadIdx.x] = v;
    __syncthreads();
    #pragma unroll
    for (int off = 1; off < SCAN_B; off <<= 1) {
        int t = (threadIdx.x >= off) ? s[threadIdx.x - off] : 0;
        __syncthreads();
        s[threadIdx.x] += t;
        __syncthreads();
    }
    if (i < n) rptr[i] = s[threadIdx.x] - v;
    if (threadIdx.x == SCAN_B - 1) bsum[blockIdx.x] = s[SCAN_B - 1];
}

__global__ __launch_bounds__(512) void scanB_kernel(int* __restrict__ bsum, int nb) {
    __shared__ int s[512];
    int t = threadIdx.x;
    int v = (t < nb) ? bsum[t] : 0;
    s[t] = v;
    __syncthreads();
    #pragma unroll
    for (int off = 1; off < 512; off <<= 1) {
        int x = (t >= off) ? s[t - off] : 0;
        __syncthreads();
        s[t] += x;
        __syncthreads();
    }
    if (t < nb) bsum[t] = s[t] - v;
}

__global__ __launch_bounds__(256) void scanC_kernel(int* __restrict__ rptr,
                                                    const int* __restrict__ bsum,
                                                    int* __restrict__ cursor,
                                                    int n, int E) {
    int i = blockIdx.x * SCAN_B + threadIdx.x;
    if (i < n) {
        rptr[i] += bsum[blockIdx.x];
        cursor[i] = 0;
    }
    if (i == 0) rptr[n] = E;
}

__global__ __launch_bounds__(256) void fill_kernel(const int* __restrict__ erow,
                                                   const int* __restrict__ ecol,
                                                   const float* __restrict__ evals,
                                                   const int* __restrict__ rptr,
                                                   int* __restrict__ cursor,
                                                   int2* __restrict__ cv, int E) {
    int e = blockIdx.x * 256 + threadIdx.x;
    if (e < E) {
        int r = erow[e];
        int p = rptr[r] + atomicAdd(&cursor[r], 1);
        cv[p] = make_int2(ecol[e], __float_as_int(evals[e]));
    }
}

// ---------------------------------------------------------------------------
// W1 [512][256] f32  ->  W1T [256][512] fp16 (transposed, MFMA B^T layout)
// ---------------------------------------------------------------------------
__global__ __launch_bounds__(256) void w1t_kernel(const float* __restrict__ W1,
                                                  _Float16* __restrict__ W1T) {
    int o = blockIdx.x * 256 + threadIdx.x;   // 0..131071
    int n = o >> 9, k = o & 511;
    W1T[o] = (_Float16)W1[(size_t)k * HIDDEN + n];
}

// ---------------------------------------------------------------------------
// GEMM1 (MFMA fp16): H1[M,256] = fp16(A[M,512]) @ fp16(W1)
// tile 64(M) x 128(N), BK=32, 4 waves (2x2), wave tile 32x64, 2x4 fragments
// ---------------------------------------------------------------------------
__global__ __launch_bounds__(256) void gemm1_mfma_kernel(const float* __restrict__ A,
                                                         const _Float16* __restrict__ BT,
                                                         _Float16* __restrict__ C, int M) {
    __shared__ __align__(16) char smem[17408];
    _Float16 (*As)[40]  = (_Float16 (*)[40])smem;             //  64x40  = 5120 B
    _Float16 (*Bs)[40]  = (_Float16 (*)[40])(smem + 5120);    // 128x40  = 10240 B
    _Float16 (*sC)[136] = (_Float16 (*)[136])smem;            //  64x136 = 17408 B (epilogue)

    const int t    = threadIdx.x;
    const int m0   = blockIdx.x * 64;
    const int n0   = blockIdx.y * 128;
    const int lane = t & 63;
    const int wid  = t >> 6;
    const int wr   = wid >> 1, wc = wid & 1;
    const int lr   = lane & 15, lk = lane >> 4;

    f32x4 acc[2][4] = {};

    const int  ar   = t >> 2;            // 0..63
    const int  aq   = t & 3;             // 0..3
    const bool aval = (m0 + ar) < M;
    const float*    aptr = A  + (size_t)(m0 + ar) * F_IN + aq * 8;
    const int       br   = t >> 1;       // 0..127
    const int       bq   = t & 1;        // 0..1
    const _Float16* bptr = BT + (size_t)(n0 + br) * F_IN + bq * 16;

    for (int k0 = 0; k0 < F_IN; k0 += 32) {
        // stage A (fp32 -> fp16)
        float4 a0 = {0.f,0.f,0.f,0.f}, a1 = {0.f,0.f,0.f,0.f};
        if (aval) {
            a0 = *(const float4*)(aptr + k0);
            a1 = *(const float4*)(aptr + k0 + 4);
        }
        half8 ah;
        ah[0]=(_Float16)a0.x; ah[1]=(_Float16)a0.y; ah[2]=(_Float16)a0.z; ah[3]=(_Float16)a0.w;
        ah[4]=(_Float16)a1.x; ah[5]=(_Float16)a1.y; ah[6]=(_Float16)a1.z; ah[7]=(_Float16)a1.w;
        *(half8*)&As[ar][aq * 8] = ah;
        // stage B (already fp16, straight copy of 32B)
        *(half8*)&Bs[br][bq * 16]     = *(const half8*)(bptr + k0);
        *(half8*)&Bs[br][bq * 16 + 8] = *(const half8*)(bptr + k0 + 8);
        __syncthreads();

        half8 af0 = *(half8*)&As[wr * 32 + lr][lk * 8];
        half8 af1 = *(half8*)&As[wr * 32 + 16 + lr][lk * 8];
        half8 bf[4];
        #pragma unroll
        for (int fn = 0; fn < 4; fn++)
            bf[fn] = *(half8*)&Bs[wc * 64 + fn * 16 + lr][lk * 8];

        #pragma unroll
        for (int fn = 0; fn < 4; fn++) {
            acc[0][fn] = __builtin_amdgcn_mfma_f32_16x16x32_f16(af0, bf[fn], acc[0][fn], 0, 0, 0);
            acc[1][fn] = __builtin_amdgcn_mfma_f32_16x16x32_f16(af1, bf[fn], acc[1][fn], 0, 0, 0);
        }
        __syncthreads();
    }

    // epilogue: acc -> LDS (fp16) -> coalesced global stores
    #pragma unroll
    for (int fm = 0; fm < 2; fm++)
        #pragma unroll
        for (int fn = 0; fn < 4; fn++)
            #pragma unroll
            for (int j = 0; j < 4; j++) {
                int row = wr * 32 + fm * 16 + lk * 4 + j;
                int col = wc * 64 + fn * 16 + lr;
                sC[row][col] = (_Float16)acc[fm][fn][j];
            }
    __syncthreads();

    int m = m0 + ar;
    if (m < M) {
        const float4* sp = (const float4*)&sC[ar][aq * 32];
        float4*       dp = (float4*)(C + (size_t)m * HIDDEN + n0 + aq * 32);
        dp[0] = sp[0]; dp[1] = sp[1]; dp[2] = sp[2]; dp[3] = sp[3];
    }
}

// ---------------------------------------------------------------------------
// SpMM gather D=256 (fp16) + ReLU: A1[r] = relu(sum_e v * H1[col])
// one wave per row, no LDS -> full occupancy
// ---------------------------------------------------------------------------
__global__ __launch_bounds__(256) void spmm_h1_kernel(const int* __restrict__ rptr,
                                                      const int2* __restrict__ cv,
                                                      const _Float16* __restrict__ H1,
                                                      _Float16* __restrict__ A1) {
    int t = threadIdx.x, wave = t >> 6, lane = t & 63;
    int r = blockIdx.x * 4 + wave;
    int e0 = rptr[r], e1 = rptr[r + 1];
    float4 acc = {0.f, 0.f, 0.f, 0.f};

    int e = e0;
    for (; e + 1 < e1; e += 2) {
        int2 p0 = cv[e], p1 = cv[e + 1];
        float v0 = __int_as_float(p0.y), v1 = __int_as_float(p1.y);
        half4 h0 = *(const half4*)(H1 + (size_t)p0.x * HIDDEN + lane * 4);
        half4 h1 = *(const half4*)(H1 + (size_t)p1.x * HIDDEN + lane * 4);
        acc.x += v0 * (float)h0[0] + v1 * (float)h1[0];
        acc.y += v0 * (float)h0[1] + v1 * (float)h1[1];
        acc.z += v0 * (float)h0[2] + v1 * (float)h1[2];
        acc.w += v0 * (float)h0[3] + v1 * (float)h1[3];
    }
    if (e < e1) {
        int2 p0 = cv[e];
        float v0 = __int_as_float(p0.y);
        half4 h0 = *(const half4*)(H1 + (size_t)p0.x * HIDDEN + lane * 4);
        acc.x += v0 * (float)h0[0];
        acc.y += v0 * (float)h0[1];
        acc.z += v0 * (float)h0[2];
        acc.w += v0 * (float)h0[3];
    }

    half4 o;
    o[0] = (_Float16)fmaxf(acc.x, 0.f);
    o[1] = (_Float16)fmaxf(acc.y, 0.f);
    o[2] = (_Float16)fmaxf(acc.z, 0.f);
    o[3] = (_Float16)fmaxf(acc.w, 0.f);
    *(half4*)(A1 + (size_t)r * HIDDEN + lane * 4) = o;
}

// ---------------------------------------------------------------------------
// GEMM2: H2[M,40] = A1(fp16, already relu'd) @ W2(fp32) ; 32 rows per block
// ---------------------------------------------------------------------------
#define G2_ROWS 32
__global__ __launch_bounds__(256) void gemm2_kernel(const _Float16* __restrict__ A1,
                                                    const float* __restrict__ W2,
                                                    _Float16* __restrict__ H2) {
    __shared__ float sA[G2_ROWS][HIDDEN];   // 32 KB
    int t  = threadIdx.x;
    int m0 = blockIdx.x * G2_ROWS;

    #pragma unroll
    for (int i = t; i < G2_ROWS * HIDDEN / 4; i += 256) {   // 2048 quads
        int row  = i >> 6;
        int coff = (i & 63) * 4;
        half4 h = *(const half4*)(A1 + (size_t)(m0 + row) * HIDDEN + coff);
        sA[row][coff + 0] = (float)h[0];
        sA[row][coff + 1] = (float)h[1];
        sA[row][coff + 2] = (float)h[2];
        sA[row][coff + 3] = (float)h[3];
    }
    __syncthreads();

    #pragma unroll
    for (int i = 0; i < 5; i++) {
        int o = t + i * 256;                // 0..1279
        int r = o / NCLASS, n = o % NCLASS;
        float acc = 0.f;
        #pragma unroll 8
        for (int k = 0; k < HIDDEN; k++)
            acc = fmaf(sA[r][k], W2[k * NCLASS + n], acc);
        H2[(size_t)(m0 + r) * NCLASS + n] = (_Float16)acc;
    }
}

// ---------------------------------------------------------------------------
// SpMM gather D=40 (fp16) + ReLU + log_softmax. One wave per row.
// ---------------------------------------------------------------------------
__global__ __launch_bounds__(256) void spmm40_ls_kernel(const int* __restrict__ rptr,
                                                        const int2* __restrict__ cv,
                                                        const _Float16* __restrict__ H2,
                                                        float* __restrict__ out) {
    int t = threadIdx.x;
    int wave = t >> 6, lane = t & 63;
    int r = blockIdx.x * 4 + wave;

    int e0 = rptr[r], e1 = rptr[r + 1];
    float acc = 0.f;

    int e = e0;
    for (; e + 1 < e1; e += 2) {
        int2 p0 = cv[e], p1 = cv[e + 1];
        float v0 = __int_as_float(p0.y), v1 = __int_as_float(p1.y);
        float x0 = 0.f, x1 = 0.f;
        if (lane < NCLASS) {
            x0 = (float)H2[(size_t)p0.x * NCLASS + lane];
            x1 = (float)H2[(size_t)p1.x * NCLASS + lane];
        }
        acc += v0 * x0 + v1 * x1;
    }
    if (e < e1) {
        int2 p0 = cv[e];
        float v0 = __int_as_float(p0.y);
        if (lane < NCLASS) acc += v0 * (float)H2[(size_t)p0.x * NCLASS + lane];
    }

    float z = (lane < NCLASS) ? fmaxf(acc, 0.f) : -INFINITY;
    float mx = z;
    #pragma unroll
    for (int off = 32; off >= 1; off >>= 1)
        mx = fmaxf(mx, __shfl_xor(mx, off));

    float ee = (lane < NCLASS) ? expf(z - mx) : 0.f;
    float s = ee;
    #pragma unroll
    for (int off = 32; off >= 1; off >>= 1)
        s += __shfl_xor(s, off);

    float lse = logf(s);
    if (lane < NCLASS)
        out[(size_t)r * NCLASS + lane] = z - mx - lse;
}

// ---------------------------------------------------------------------------
extern "C" void kernel_launch(void* const* d_in, const int* in_sizes, int n_in,
                              void* d_out, int out_size, void* d_ws, size_t ws_size,
                              hipStream_t stream) {
    const float* x     = (const float*)d_in[0];
    const int*   erow  = (const int*)d_in[1];
    const int*   ecol  = (const int*)d_in[2];
    const float* evals = (const float*)d_in[3];
    const float* W1    = (const float*)d_in[4];
    const float* W2    = (const float*)d_in[5];
    float* out = (float*)d_out;

    const int M = N_NODES;
    const int E = N_EDGES;

    // workspace layout (~137 MB)
    char* p = (char*)d_ws;
    auto alloc = [&](size_t bytes) {
        char* q = p;
        p += (bytes + 255) & ~(size_t)255;
        return q;
    };
    int*      deg  = (int*)alloc(sizeof(int) * N_NODES);          // doubles as cursor
    int*      rptr = (int*)alloc(sizeof(int) * (N_NODES + 1));
    int*      bsum = (int*)alloc(sizeof(int) * 512);
    int2*     cv   = (int2*)alloc(sizeof(int2) * N_EDGES);        // 25.6 MB
    _Float16* W1T  = (_Float16*)alloc(sizeof(_Float16) * F_IN * HIDDEN);        // 0.25 MB
    _Float16* H1   = (_Float16*)alloc(sizeof(_Float16) * (size_t)N_NODES * HIDDEN); // 51.2 MB
    _Float16* A1   = (_Float16*)alloc(sizeof(_Float16) * (size_t)N_NODES * HIDDEN); // 51.2 MB
    _Float16* H2   = (_Float16*)alloc(sizeof(_Float16) * (size_t)N_NODES * NCLASS); // 8 MB

    // --- CSR build ---
    hipMemsetAsync(deg, 0, sizeof(int) * N_NODES, stream);
    hist_kernel<<<E / 256, 256, 0, stream>>>(erow, deg, E);
    scanA_kernel<<<N_SCANB, SCAN_B, 0, stream>>>(deg, rptr, bsum, N_NODES);
    scanB_kernel<<<1, 512, 0, stream>>>(bsum, N_SCANB);
    scanC_kernel<<<N_SCANB, SCAN_B, 0, stream>>>(rptr, bsum, deg, N_NODES, E);
    fill_kernel<<<E / 256, 256, 0, stream>>>(erow, ecol, evals, rptr, deg, cv, E);

    // --- W1 -> fp16 transposed ---
    w1t_kernel<<<(F_IN * HIDDEN) / 256, 256, 0, stream>>>(W1, W1T);

    // --- layer 1 projection (MFMA fp16) ---
    dim3 g1((M + 63) / 64, HIDDEN / 128);
    gemm1_mfma_kernel<<<g1, 256, 0, stream>>>(x, W1T, H1, M);

    // --- layer 1 aggregation + relu (gather) ---
    spmm_h1_kernel<<<M / 4, 256, 0, stream>>>(rptr, cv, H1, A1);

    // --- layer 2 projection ---
    gemm2_kernel<<<M / G2_ROWS, 256, 0, stream>>>(A1, W2, H2);

    // --- layer 2 aggregation + relu + log_softmax ---
    spmm40_ls_kernel<<<M / 4, 256, 0, stream>>>(rptr, cv, H2, out);
}

// Round 4
// 749.770 us; speedup vs baseline: 15.7597x; 1.2953x over previous
//
#include <hip/hip_runtime.h>
#include <math.h>

#define N_NODES 100000
#define N_EDGES 3200000
#define F_IN    512
#define HIDDEN  256
#define NCLASS  40
#define NPAD    48

#define SCAN_B  256
#define N_SCANB ((N_NODES + SCAN_B - 1) / SCAN_B)   // 391

typedef __attribute__((ext_vector_type(8))) _Float16 half8;
typedef __attribute__((ext_vector_type(4))) _Float16 half4;
typedef __attribute__((ext_vector_type(4))) float    f32x4;

// ---------------------------------------------------------------------------
// CSR build
// ---------------------------------------------------------------------------
__global__ __launch_bounds__(256) void hist_kernel(const int* __restrict__ erow,
                                                   int* __restrict__ deg, int E) {
    int e = blockIdx.x * 256 + threadIdx.x;
    if (e < E) atomicAdd(&deg[erow[e]], 1);
}

__global__ __launch_bounds__(256) void scanA_kernel(const int* __restrict__ deg,
                                                    int* __restrict__ rptr,
                                                    int* __restrict__ bsum, int n) {
    __shared__ int s[SCAN_B];
    int i = blockIdx.x * SCAN_B + threadIdx.x;
    int v = (i < n) ? deg[i] : 0;
    s[threadIdx.x] = v;
    __syncthreads();
    #pragma unroll
    for (int off = 1; off < SCAN_B; off <<= 1) {
        int t = (threadIdx.x >= off) ? s[threadIdx.x - off] : 0;
        __syncthreads();
        s[threadIdx.x] += t;
        __syncthreads();
    }
    if (i < n) rptr[i] = s[threadIdx.x] - v;
    if (threadIdx.x == SCAN_B - 1) bsum[blockIdx.x] = s[SCAN_B - 1];
}

__global__ __launch_bounds__(512) void scanB_kernel(int* __restrict__ bsum, int nb) {
    __shared__ int s[512];
    int t = threadIdx.x;
    int v = (t < nb) ? bsum[t] : 0;
    s[t] = v;
    __syncthreads();
    #pragma unroll
    for (int off = 1; off < 512; off <<= 1) {
        int x = (t >= off) ? s[t - off] : 0;
        __syncthreads();
        s[t] += x;
        __syncthreads();
    }
    if (t < nb) bsum[t] = s[t] - v;
}

__global__ __launch_bounds__(256) void scanC_kernel(int* __restrict__ rptr,
                                                    const int* __restrict__ bsum,
                                                    int* __restrict__ cursor,
                                                    int n, int E) {
    int i = blockIdx.x * SCAN_B + threadIdx.x;
    if (i < n) {
        rptr[i] += bsum[blockIdx.x];
        cursor[i] = 0;
    }
    if (i == 0) rptr[n] = E;
}

__global__ __launch_bounds__(256) void fill_kernel(const int* __restrict__ erow,
                                                   const int* __restrict__ ecol,
                                                   const float* __restrict__ evals,
                                                   const int* __restrict__ rptr,
                                                   int* __restrict__ cursor,
                                                   int2* __restrict__ cv, int E) {
    int e = blockIdx.x * 256 + threadIdx.x;
    if (e < E) {
        int r = erow[e];
        int p = rptr[r] + atomicAdd(&cursor[r], 1);
        cv[p] = make_int2(ecol[e], __float_as_int(evals[e]));
    }
}

// ---------------------------------------------------------------------------
// W1 [512][256] f32  ->  W1T [256][512] fp16 ;  W2 [256][40] f32 -> W2T [48][256] fp16
// ---------------------------------------------------------------------------
__global__ __launch_bounds__(256) void w1t_kernel(const float* __restrict__ W1,
                                                  _Float16* __restrict__ W1T) {
    int o = blockIdx.x * 256 + threadIdx.x;   // 0..131071
    int n = o >> 9, k = o & 511;
    W1T[o] = (_Float16)W1[(size_t)k * HIDDEN + n];
}

__global__ __launch_bounds__(256) void w2t_kernel(const float* __restrict__ W2,
                                                  _Float16* __restrict__ W2T) {
    int o = blockIdx.x * 256 + threadIdx.x;   // 0..12287
    int n = o >> 8, k = o & 255;
    W2T[o] = (n < NCLASS) ? (_Float16)W2[(size_t)k * NCLASS + n] : (_Float16)0.f;
}

// ---------------------------------------------------------------------------
// GEMM1 (MFMA fp16): H1[M,256] = fp16(A[M,512]) @ fp16(W1)
// tile 64(M) x 256(N) -- x is read exactly ONCE. 4 waves (2Mx2N), wave 32x128.
// ---------------------------------------------------------------------------
__global__ __launch_bounds__(256) void gemm1_mfma_kernel(const float* __restrict__ A,
                                                         const _Float16* __restrict__ BT,
                                                         _Float16* __restrict__ C, int M) {
    __shared__ __align__(16) char smem[33792];
    _Float16 (*As)[40]  = (_Float16 (*)[40])smem;              //  64x40  = 5120 B
    _Float16 (*Bs)[40]  = (_Float16 (*)[40])(smem + 5120);     // 256x40  = 20480 B
    _Float16 (*sC)[264] = (_Float16 (*)[264])smem;             //  64x264 = 33792 B (epilogue)

    const int t    = threadIdx.x;
    const int m0   = blockIdx.x * 64;
    const int lane = t & 63;
    const int wid  = t >> 6;
    const int wr   = wid >> 1, wc = wid & 1;
    const int lr   = lane & 15, lk = lane >> 4;

    f32x4 acc[2][8] = {};

    const int  ar   = t >> 2;            // 0..63
    const int  aq   = t & 3;             // 0..3
    const bool aval = (m0 + ar) < M;
    const float*    aptr = A  + (size_t)(m0 + ar) * F_IN + aq * 8;
    const _Float16* bptr = BT + (size_t)t * F_IN;              // row t of BT

    for (int k0 = 0; k0 < F_IN; k0 += 32) {
        // stage A (fp32 -> fp16): 64 rows x 32 k
        float4 a0 = {0.f,0.f,0.f,0.f}, a1 = {0.f,0.f,0.f,0.f};
        if (aval) {
            a0 = *(const float4*)(aptr + k0);
            a1 = *(const float4*)(aptr + k0 + 4);
        }
        half8 ah;
        ah[0]=(_Float16)a0.x; ah[1]=(_Float16)a0.y; ah[2]=(_Float16)a0.z; ah[3]=(_Float16)a0.w;
        ah[4]=(_Float16)a1.x; ah[5]=(_Float16)a1.y; ah[6]=(_Float16)a1.z; ah[7]=(_Float16)a1.w;
        *(half8*)&As[ar][aq * 8] = ah;
        // stage B: 256 rows x 32 k, 64 B per thread
        {
            const half8* bp = (const half8*)(bptr + k0);
            *(half8*)&Bs[t][0]  = bp[0];
            *(half8*)&Bs[t][8]  = bp[1];
            *(half8*)&Bs[t][16] = bp[2];
            *(half8*)&Bs[t][24] = bp[3];
        }
        __syncthreads();

        half8 af0 = *(half8*)&As[wr * 32 + lr][lk * 8];
        half8 af1 = *(half8*)&As[wr * 32 + 16 + lr][lk * 8];
        #pragma unroll
        for (int fn = 0; fn < 8; fn++) {
            half8 bf = *(half8*)&Bs[wc * 128 + fn * 16 + lr][lk * 8];
            acc[0][fn] = __builtin_amdgcn_mfma_f32_16x16x32_f16(af0, bf, acc[0][fn], 0, 0, 0);
            acc[1][fn] = __builtin_amdgcn_mfma_f32_16x16x32_f16(af1, bf, acc[1][fn], 0, 0, 0);
        }
        __syncthreads();
    }

    // epilogue: acc -> LDS (fp16) -> coalesced global stores
    #pragma unroll
    for (int fm = 0; fm < 2; fm++)
        #pragma unroll
        for (int fn = 0; fn < 8; fn++)
            #pragma unroll
            for (int j = 0; j < 4; j++) {
                int row = wr * 32 + fm * 16 + lk * 4 + j;
                int col = wc * 128 + fn * 16 + lr;
                sC[row][col] = (_Float16)acc[fm][fn][j];
            }
    __syncthreads();

    int m = m0 + ar;
    if (m < M) {
        const float4* sp = (const float4*)&sC[ar][aq * 64];
        float4*       dp = (float4*)(C + (size_t)m * HIDDEN + aq * 64);
        #pragma unroll
        for (int j = 0; j < 8; j++) dp[j] = sp[j];
    }
}

// ---------------------------------------------------------------------------
// SpMM gather D=256 (fp16) + ReLU, one wave per row, unroll 4
// ---------------------------------------------------------------------------
__global__ __launch_bounds__(256) void spmm_h1_kernel(const int* __restrict__ rptr,
                                                      const int2* __restrict__ cv,
                                                      const _Float16* __restrict__ H1,
                                                      _Float16* __restrict__ A1) {
    int t = threadIdx.x, wave = t >> 6, lane = t & 63;
    int r = blockIdx.x * 4 + wave;
    int e0 = rptr[r], e1 = rptr[r + 1];
    float4 acc = {0.f, 0.f, 0.f, 0.f};

    int e = e0;
    for (; e + 3 < e1; e += 4) {
        int2 p0 = cv[e], p1 = cv[e + 1], p2 = cv[e + 2], p3 = cv[e + 3];
        half4 h0 = *(const half4*)(H1 + (size_t)p0.x * HIDDEN + lane * 4);
        half4 h1 = *(const half4*)(H1 + (size_t)p1.x * HIDDEN + lane * 4);
        half4 h2 = *(const half4*)(H1 + (size_t)p2.x * HIDDEN + lane * 4);
        half4 h3 = *(const half4*)(H1 + (size_t)p3.x * HIDDEN + lane * 4);
        float v0 = __int_as_float(p0.y), v1 = __int_as_float(p1.y);
        float v2 = __int_as_float(p2.y), v3 = __int_as_float(p3.y);
        acc.x += v0*(float)h0[0] + v1*(float)h1[0] + v2*(float)h2[0] + v3*(float)h3[0];
        acc.y += v0*(float)h0[1] + v1*(float)h1[1] + v2*(float)h2[1] + v3*(float)h3[1];
        acc.z += v0*(float)h0[2] + v1*(float)h1[2] + v2*(float)h2[2] + v3*(float)h3[2];
        acc.w += v0*(float)h0[3] + v1*(float)h1[3] + v2*(float)h2[3] + v3*(float)h3[3];
    }
    for (; e < e1; e++) {
        int2 p0 = cv[e];
        float v0 = __int_as_float(p0.y);
        half4 h0 = *(const half4*)(H1 + (size_t)p0.x * HIDDEN + lane * 4);
        acc.x += v0*(float)h0[0];
        acc.y += v0*(float)h0[1];
        acc.z += v0*(float)h0[2];
        acc.w += v0*(float)h0[3];
    }

    half4 o;
    o[0] = (_Float16)fmaxf(acc.x, 0.f);
    o[1] = (_Float16)fmaxf(acc.y, 0.f);
    o[2] = (_Float16)fmaxf(acc.z, 0.f);
    o[3] = (_Float16)fmaxf(acc.w, 0.f);
    *(half4*)(A1 + (size_t)r * HIDDEN + lane * 4) = o;
}

// ---------------------------------------------------------------------------
// GEMM2 (MFMA fp16): H2[M,40] = A1[M,256] @ W2 ; tile 64(M) x 48(N), whole K
// ---------------------------------------------------------------------------
__global__ __launch_bounds__(256) void gemm2_mfma_kernel(const _Float16* __restrict__ A1,
                                                         const _Float16* __restrict__ W2T,
                                                         _Float16* __restrict__ H2, int M) {
    __shared__ _Float16 As[64][264];   // 33792 B
    __shared__ _Float16 Bs[48][264];   // 25344 B

    const int t    = threadIdx.x;
    const int m0   = blockIdx.x * 64;
    const int lane = t & 63;
    const int wid  = t >> 6;
    const int lr   = lane & 15, lk = lane >> 4;

    // stage B: 48 rows x 256 k
    #pragma unroll
    for (int i = 0; i < 6; i++) {
        int idx = t + i * 256;          // 0..1535
        int row = idx >> 5, c8 = idx & 31;
        *(half8*)&Bs[row][c8 * 8] = *(const half8*)(W2T + (size_t)row * HIDDEN + c8 * 8);
    }
    // stage A: 64 rows x 256 k
    {
        int ar = t >> 2, aq = t & 3;
        bool aval = (m0 + ar) < M;
        #pragma unroll
        for (int j = 0; j < 8; j++) {
            half8 v = aval ? *(const half8*)(A1 + (size_t)(m0 + ar) * HIDDEN + aq * 64 + j * 8)
                           : (half8)(_Float16)0.f;
            *(half8*)&As[ar][aq * 64 + j * 8] = v;
        }
    }
    __syncthreads();

    f32x4 acc[3] = {};
    #pragma unroll
    for (int ks = 0; ks < 8; ks++) {
        half8 af = *(half8*)&As[wid * 16 + lr][ks * 32 + lk * 8];
        #pragma unroll
        for (int fn = 0; fn < 3; fn++) {
            half8 bf = *(half8*)&Bs[fn * 16 + lr][ks * 32 + lk * 8];
            acc[fn] = __builtin_amdgcn_mfma_f32_16x16x32_f16(af, bf, acc[fn], 0, 0, 0);
        }
    }

    #pragma unroll
    for (int fn = 0; fn < 3; fn++)
        #pragma unroll
        for (int j = 0; j < 4; j++) {
            int row = wid * 16 + lk * 4 + j;
            int col = fn * 16 + lr;
            int m = m0 + row;
            if (col < NCLASS && m < M)
                H2[(size_t)m * NCLASS + col] = (_Float16)acc[fn][j];
        }
}

// ---------------------------------------------------------------------------
// SpMM gather D=40 (fp16) + ReLU + log_softmax. One wave per row,
// 6 edges x 10 lanes (4 classes each) per iteration.
// ---------------------------------------------------------------------------
__global__ __launch_bounds__(256) void spmm40_ls_kernel(const int* __restrict__ rptr,
                                                        const int2* __restrict__ cv,
                                                        const _Float16* __restrict__ H2,
                                                        float* __restrict__ out) {
    int t = threadIdx.x;
    int wave = t >> 6, lane = t & 63;
    int r = blockIdx.x * 4 + wave;

    int e0 = rptr[r], e1 = rptr[r + 1];
    int s = lane / 10;          // edge slot 0..5 (6 = inactive)
    int g = lane % 10;          // class group: classes g*4 .. g*4+3
    bool lact = lane < 60;

    float4 acc = {0.f, 0.f, 0.f, 0.f};
    for (int e = e0; e < e1; e += 6) {
        int idx = e + s;
        bool val = lact && (idx < e1);
        float v = 0.f;
        half4 h = (half4)(_Float16)0.f;
        if (val) {
            int2 p = cv[idx];
            v = __int_as_float(p.y);
            h = *(const half4*)(H2 + (size_t)p.x * NCLASS + g * 4);
        }
        acc.x += v * (float)h[0];
        acc.y += v * (float)h[1];
        acc.z += v * (float)h[2];
        acc.w += v * (float)h[3];
    }

    // reduce slots: lane g += lanes g+30 ; then g+10, g+20
    {
        float4 t3;
        t3.x = __shfl(acc.x, lane + 30);
        t3.y = __shfl(acc.y, lane + 30);
        t3.z = __shfl(acc.z, lane + 30);
        t3.w = __shfl(acc.w, lane + 30);
        acc.x += t3.x; acc.y += t3.y; acc.z += t3.z; acc.w += t3.w;
        float4 t1, t2;
        t1.x = __shfl(acc.x, lane + 10); t2.x = __shfl(acc.x, lane + 20);
        t1.y = __shfl(acc.y, lane + 10); t2.y = __shfl(acc.y, lane + 20);
        t1.z = __shfl(acc.z, lane + 10); t2.z = __shfl(acc.z, lane + 20);
        t1.w = __shfl(acc.w, lane + 10); t2.w = __shfl(acc.w, lane + 20);
        acc.x += t1.x + t2.x; acc.y += t1.y + t2.y;
        acc.z += t1.z + t2.z; acc.w += t1.w + t2.w;
    }

    // lanes 0..9 hold the 40 aggregated values (4 each)
    bool act = lane < 10;
    float z0 = act ? fmaxf(acc.x, 0.f) : -INFINITY;
    float z1 = act ? fmaxf(acc.y, 0.f) : -INFINITY;
    float z2 = act ? fmaxf(acc.z, 0.f) : -INFINITY;
    float z3 = act ? fmaxf(acc.w, 0.f) : -INFINITY;

    float mx = fmaxf(fmaxf(z0, z1), fmaxf(z2, z3));
    #pragma unroll
    for (int off = 1; off <= 8; off <<= 1)
        mx = fmaxf(mx, __shfl_xor(mx, off));   // max over 16-lane group

    float sum = act ? (expf(z0 - mx) + expf(z1 - mx) + expf(z2 - mx) + expf(z3 - mx)) : 0.f;
    #pragma unroll
    for (int off = 1; off <= 8; off <<= 1)
        sum += __shfl_xor(sum, off);

    float lse = logf(sum);
    if (act) {
        float4 o = {z0 - mx - lse, z1 - mx - lse, z2 - mx - lse, z3 - mx - lse};
        *(float4*)(out + (size_t)r * NCLASS + lane * 4) = o;
    }
}

// ---------------------------------------------------------------------------
extern "C" void kernel_launch(void* const* d_in, const int* in_sizes, int n_in,
                              void* d_out, int out_size, void* d_ws, size_t ws_size,
                              hipStream_t stream) {
    const float* x     = (const float*)d_in[0];
    const int*   erow  = (const int*)d_in[1];
    const int*   ecol  = (const int*)d_in[2];
    const float* evals = (const float*)d_in[3];
    const float* W1    = (const float*)d_in[4];
    const float* W2    = (const float*)d_in[5];
    float* out = (float*)d_out;

    const int M = N_NODES;
    const int E = N_EDGES;

    char* p = (char*)d_ws;
    auto alloc = [&](size_t bytes) {
        char* q = p;
        p += (bytes + 255) & ~(size_t)255;
        return q;
    };
    int*      deg  = (int*)alloc(sizeof(int) * N_NODES);          // doubles as cursor
    int*      rptr = (int*)alloc(sizeof(int) * (N_NODES + 1));
    int*      bsum = (int*)alloc(sizeof(int) * 512);
    int2*     cv   = (int2*)alloc(sizeof(int2) * N_EDGES);        // 25.6 MB
    _Float16* W1T  = (_Float16*)alloc(sizeof(_Float16) * F_IN * HIDDEN);
    _Float16* W2T  = (_Float16*)alloc(sizeof(_Float16) * NPAD * HIDDEN);
    _Float16* H1   = (_Float16*)alloc(sizeof(_Float16) * (size_t)N_NODES * HIDDEN); // 51.2 MB
    _Float16* A1   = (_Float16*)alloc(sizeof(_Float16) * (size_t)N_NODES * HIDDEN); // 51.2 MB
    _Float16* H2   = (_Float16*)alloc(sizeof(_Float16) * (size_t)N_NODES * NCLASS); // 8 MB

    // --- CSR build ---
    hipMemsetAsync(deg, 0, sizeof(int) * N_NODES, stream);
    hist_kernel<<<E / 256, 256, 0, stream>>>(erow, deg, E);
    scanA_kernel<<<N_SCANB, SCAN_B, 0, stream>>>(deg, rptr, bsum, N_NODES);
    scanB_kernel<<<1, 512, 0, stream>>>(bsum, N_SCANB);
    scanC_kernel<<<N_SCANB, SCAN_B, 0, stream>>>(rptr, bsum, deg, N_NODES, E);
    fill_kernel<<<E / 256, 256, 0, stream>>>(erow, ecol, evals, rptr, deg, cv, E);

    // --- weight conversions ---
    w1t_kernel<<<(F_IN * HIDDEN) / 256, 256, 0, stream>>>(W1, W1T);
    w2t_kernel<<<(NPAD * HIDDEN) / 256, 256, 0, stream>>>(W2, W2T);

    // --- layer 1 projection (MFMA fp16, x read once) ---
    gemm1_mfma_kernel<<<(M + 63) / 64, 256, 0, stream>>>(x, W1T, H1, M);

    // --- layer 1 aggregation + relu (gather) ---
    spmm_h1_kernel<<<M / 4, 256, 0, stream>>>(rptr, cv, H1, A1);

    // --- layer 2 projection (MFMA) ---
    gemm2_mfma_kernel<<<(M + 63) / 64, 256, 0, stream>>>(A1, W2T, H2, M);

    // --- layer 2 aggregation + relu + log_softmax ---
    spmm40_ls_kernel<<<M / 4, 256, 0, stream>>>(rptr, cv, H2, out);
}

// Round 5
// 662.024 us; speedup vs baseline: 17.8485x; 1.1325x over previous
//
#include <hip/hip_runtime.h>
#include <math.h>

#define N_NODES 100000
#define N_EDGES 3200000
#define F_IN    512
#define HIDDEN  256
#define NCLASS  40
#define NPAD    48

#define SCAN_B  256
#define N_SCANB ((N_NODES + SCAN_B - 1) / SCAN_B)   // 391

typedef __attribute__((ext_vector_type(8))) _Float16 half8;
typedef __attribute__((ext_vector_type(4))) _Float16 half4;
typedef __attribute__((ext_vector_type(4))) float    f32x4;

// ---------------------------------------------------------------------------
// CSR build: pass 1 = histogram + per-edge rank (atomic return value)
// ---------------------------------------------------------------------------
__global__ __launch_bounds__(256) void hist2_kernel(const int* __restrict__ erow,
                                                    int* __restrict__ deg,
                                                    unsigned short* __restrict__ ke, int E) {
    int e = blockIdx.x * 256 + threadIdx.x;
    if (e < E) ke[e] = (unsigned short)atomicAdd(&deg[erow[e]], 1);
}

__global__ __launch_bounds__(256) void scanA_kernel(const int* __restrict__ deg,
                                                    int* __restrict__ rptr,
                                                    int* __restrict__ bsum, int n) {
    __shared__ int s[SCAN_B];
    int i = blockIdx.x * SCAN_B + threadIdx.x;
    int v = (i < n) ? deg[i] : 0;
    s[threadIdx.x] = v;
    __syncthreads();
    #pragma unroll
    for (int off = 1; off < SCAN_B; off <<= 1) {
        int t = (threadIdx.x >= off) ? s[threadIdx.x - off] : 0;
        __syncthreads();
        s[threadIdx.x] += t;
        __syncthreads();
    }
    if (i < n) rptr[i] = s[threadIdx.x] - v;
    if (threadIdx.x == SCAN_B - 1) bsum[blockIdx.x] = s[SCAN_B - 1];
}

__global__ __launch_bounds__(512) void scanB_kernel(int* __restrict__ bsum, int nb) {
    __shared__ int s[512];
    int t = threadIdx.x;
    int v = (t < nb) ? bsum[t] : 0;
    s[t] = v;
    __syncthreads();
    #pragma unroll
    for (int off = 1; off < 512; off <<= 1) {
        int x = (t >= off) ? s[t - off] : 0;
        __syncthreads();
        s[t] += x;
        __syncthreads();
    }
    if (t < nb) bsum[t] = s[t] - v;
}

__global__ __launch_bounds__(256) void scanC_kernel(int* __restrict__ rptr,
                                                    const int* __restrict__ bsum,
                                                    int n, int E) {
    int i = blockIdx.x * SCAN_B + threadIdx.x;
    if (i < n) rptr[i] += bsum[blockIdx.x];
    if (i == 0) rptr[n] = E;
}

// pass 2: permute (col,val) -> CSR slots, NO atomics
__global__ __launch_bounds__(256) void fill2_kernel(const int* __restrict__ erow,
                                                    const int* __restrict__ ecol,
                                                    const float* __restrict__ evals,
                                                    const int* __restrict__ rptr,
                                                    const unsigned short* __restrict__ ke,
                                                    int2* __restrict__ cv, int E) {
    int e = blockIdx.x * 256 + threadIdx.x;
    if (e < E) {
        int p = rptr[erow[e]] + ke[e];
        cv[p] = make_int2(ecol[e], __float_as_int(evals[e]));
    }
}

// ---------------------------------------------------------------------------
// W1 [512][256] f32  ->  W1T [256][512] fp16 ;  W2 [256][40] f32 -> W2T [48][256] fp16
// ---------------------------------------------------------------------------
__global__ __launch_bounds__(256) void w1t_kernel(const float* __restrict__ W1,
                                                  _Float16* __restrict__ W1T) {
    int o = blockIdx.x * 256 + threadIdx.x;   // 0..131071
    int n = o >> 9, k = o & 511;
    W1T[o] = (_Float16)W1[(size_t)k * HIDDEN + n];
}

__global__ __launch_bounds__(256) void w2t_kernel(const float* __restrict__ W2,
                                                  _Float16* __restrict__ W2T) {
    int o = blockIdx.x * 256 + threadIdx.x;   // 0..12287
    int n = o >> 8, k = o & 255;
    W2T[o] = (n < NCLASS) ? (_Float16)W2[(size_t)k * NCLASS + n] : (_Float16)0.f;
}

// ---------------------------------------------------------------------------
// GEMM1 (MFMA fp16): H1[M,256] = fp16(A[M,512]) @ fp16(W1)
// tile 64(M) x 256(N) -- x read exactly once. 4 waves (2Mx2N), wave 32x128.
// ---------------------------------------------------------------------------
__global__ __launch_bounds__(256) void gemm1_mfma_kernel(const float* __restrict__ A,
                                                         const _Float16* __restrict__ BT,
                                                         _Float16* __restrict__ C, int M) {
    __shared__ __align__(16) char smem[33792];
    _Float16 (*As)[40]  = (_Float16 (*)[40])smem;              //  64x40  = 5120 B
    _Float16 (*Bs)[40]  = (_Float16 (*)[40])(smem + 5120);     // 256x40  = 20480 B
    _Float16 (*sC)[264] = (_Float16 (*)[264])smem;             //  64x264 = 33792 B (epilogue)

    const int t    = threadIdx.x;
    const int m0   = blockIdx.x * 64;
    const int lane = t & 63;
    const int wid  = t >> 6;
    const int wr   = wid >> 1, wc = wid & 1;
    const int lr   = lane & 15, lk = lane >> 4;

    f32x4 acc[2][8] = {};

    const int  ar   = t >> 2;            // 0..63
    const int  aq   = t & 3;             // 0..3
    const bool aval = (m0 + ar) < M;
    const float*    aptr = A  + (size_t)(m0 + ar) * F_IN + aq * 8;
    const _Float16* bptr = BT + (size_t)t * F_IN;              // row t of BT

    for (int k0 = 0; k0 < F_IN; k0 += 32) {
        float4 a0 = {0.f,0.f,0.f,0.f}, a1 = {0.f,0.f,0.f,0.f};
        if (aval) {
            a0 = *(const float4*)(aptr + k0);
            a1 = *(const float4*)(aptr + k0 + 4);
        }
        half8 ah;
        ah[0]=(_Float16)a0.x; ah[1]=(_Float16)a0.y; ah[2]=(_Float16)a0.z; ah[3]=(_Float16)a0.w;
        ah[4]=(_Float16)a1.x; ah[5]=(_Float16)a1.y; ah[6]=(_Float16)a1.z; ah[7]=(_Float16)a1.w;
        *(half8*)&As[ar][aq * 8] = ah;
        {
            const half8* bp = (const half8*)(bptr + k0);
            *(half8*)&Bs[t][0]  = bp[0];
            *(half8*)&Bs[t][8]  = bp[1];
            *(half8*)&Bs[t][16] = bp[2];
            *(half8*)&Bs[t][24] = bp[3];
        }
        __syncthreads();

        half8 af0 = *(half8*)&As[wr * 32 + lr][lk * 8];
        half8 af1 = *(half8*)&As[wr * 32 + 16 + lr][lk * 8];
        #pragma unroll
        for (int fn = 0; fn < 8; fn++) {
            half8 bf = *(half8*)&Bs[wc * 128 + fn * 16 + lr][lk * 8];
            acc[0][fn] = __builtin_amdgcn_mfma_f32_16x16x32_f16(af0, bf, acc[0][fn], 0, 0, 0);
            acc[1][fn] = __builtin_amdgcn_mfma_f32_16x16x32_f16(af1, bf, acc[1][fn], 0, 0, 0);
        }
        __syncthreads();
    }

    #pragma unroll
    for (int fm = 0; fm < 2; fm++)
        #pragma unroll
        for (int fn = 0; fn < 8; fn++)
            #pragma unroll
            for (int j = 0; j < 4; j++) {
                int row = wr * 32 + fm * 16 + lk * 4 + j;
                int col = wc * 128 + fn * 16 + lr;
                sC[row][col] = (_Float16)acc[fm][fn][j];
            }
    __syncthreads();

    int m = m0 + ar;
    if (m < M) {
        const float4* sp = (const float4*)&sC[ar][aq * 64];
        float4*       dp = (float4*)(C + (size_t)m * HIDDEN + aq * 64);
        #pragma unroll
        for (int j = 0; j < 8; j++) dp[j] = sp[j];
    }
}

// ---------------------------------------------------------------------------
// SpMM gather D=256 (fp16) + ReLU. One wave per row; 2 edges per gather
// instruction (32 lanes x 16B cover one 512B row), unroll 4 = 8 edges in flight.
// ---------------------------------------------------------------------------
__global__ __launch_bounds__(256) void spmm_h1_kernel(const int* __restrict__ rptr,
                                                      const int2* __restrict__ cv,
                                                      const _Float16* __restrict__ H1,
                                                      _Float16* __restrict__ A1) {
    int t = threadIdx.x, wave = t >> 6, lane = t & 63;
    int r = blockIdx.x * 4 + wave;
    int e0 = rptr[r], e1 = rptr[r + 1];
    int hf = lane >> 5;            // 0/1: which edge of the pair
    int fl = lane & 31;            // feature block (8 fp16 each)

    float acc[8] = {};

    for (int e = e0; e < e1; e += 8) {
        #pragma unroll
        for (int u = 0; u < 4; u++) {
            int idx = e + 2 * u + hf;
            bool ok = idx < e1;
            int2 p = cv[ok ? idx : e0];
            float v = ok ? __int_as_float(p.y) : 0.f;
            half8 h = *(const half8*)(H1 + (size_t)p.x * HIDDEN + fl * 8);
            #pragma unroll
            for (int j = 0; j < 8; j++)
                acc[j] += v * (float)h[j];
        }
    }

    // merge the two half-wave edge groups
    #pragma unroll
    for (int j = 0; j < 8; j++)
        acc[j] += __shfl_xor(acc[j], 32);

    if (hf == 0) {
        half8 o;
        #pragma unroll
        for (int j = 0; j < 8; j++) o[j] = (_Float16)fmaxf(acc[j], 0.f);
        *(half8*)(A1 + (size_t)r * HIDDEN + fl * 8) = o;
    }
}

// ---------------------------------------------------------------------------
// GEMM2 (MFMA fp16): H2[M,40] = A1[M,256] @ W2 ; tile 64(M) x 48(N), whole K
// ---------------------------------------------------------------------------
__global__ __launch_bounds__(256) void gemm2_mfma_kernel(const _Float16* __restrict__ A1,
                                                         const _Float16* __restrict__ W2T,
                                                         _Float16* __restrict__ H2, int M) {
    __shared__ _Float16 As[64][264];   // 33792 B
    __shared__ _Float16 Bs[48][264];   // 25344 B

    const int t    = threadIdx.x;
    const int m0   = blockIdx.x * 64;
    const int lane = t & 63;
    const int wid  = t >> 6;
    const int lr   = lane & 15, lk = lane >> 4;

    #pragma unroll
    for (int i = 0; i < 6; i++) {
        int idx = t + i * 256;          // 0..1535
        int row = idx >> 5, c8 = idx & 31;
        *(half8*)&Bs[row][c8 * 8] = *(const half8*)(W2T + (size_t)row * HIDDEN + c8 * 8);
    }
    {
        int ar = t >> 2, aq = t & 3;
        bool aval = (m0 + ar) < M;
        #pragma unroll
        for (int j = 0; j < 8; j++) {
            half8 v = aval ? *(const half8*)(A1 + (size_t)(m0 + ar) * HIDDEN + aq * 64 + j * 8)
                           : (half8)(_Float16)0.f;
            *(half8*)&As[ar][aq * 64 + j * 8] = v;
        }
    }
    __syncthreads();

    f32x4 acc[3] = {};
    #pragma unroll
    for (int ks = 0; ks < 8; ks++) {
        half8 af = *(half8*)&As[wid * 16 + lr][ks * 32 + lk * 8];
        #pragma unroll
        for (int fn = 0; fn < 3; fn++) {
            half8 bf = *(half8*)&Bs[fn * 16 + lr][ks * 32 + lk * 8];
            acc[fn] = __builtin_amdgcn_mfma_f32_16x16x32_f16(af, bf, acc[fn], 0, 0, 0);
        }
    }

    #pragma unroll
    for (int fn = 0; fn < 3; fn++)
        #pragma unroll
        for (int j = 0; j < 4; j++) {
            int row = wid * 16 + lk * 4 + j;
            int col = fn * 16 + lr;
            int m = m0 + row;
            if (col < NCLASS && m < M)
                H2[(size_t)m * NCLASS + col] = (_Float16)acc[fn][j];
        }
}

// ---------------------------------------------------------------------------
// SpMM gather D=40 (fp16) + ReLU + log_softmax. One wave per row;
// 12 edges/iter, 5 lanes x half8 (16B) per edge.
// ---------------------------------------------------------------------------
__global__ __launch_bounds__(256) void spmm40_ls_kernel(const int* __restrict__ rptr,
                                                        const int2* __restrict__ cv,
                                                        const _Float16* __restrict__ H2,
                                                        float* __restrict__ out) {
    int t = threadIdx.x;
    int wave = t >> 6, lane = t & 63;
    int r = blockIdx.x * 4 + wave;

    int e0 = rptr[r], e1 = rptr[r + 1];
    int s = lane / 5;           // edge slot 0..11 (lane 60..63 -> s=12, inactive)
    int g = lane % 5;           // feature block: classes g*8 .. g*8+7
    bool lact = lane < 60;

    float acc[8] = {};
    for (int e = e0; e < e1; e += 12) {
        int idx = e + s;
        bool ok = lact && (idx < e1);
        int2 p = cv[ok ? idx : e0];
        float v = ok ? __int_as_float(p.y) : 0.f;
        half8 h = *(const half8*)(H2 + (size_t)p.x * NCLASS + g * 8);
        #pragma unroll
        for (int j = 0; j < 8; j++)
            acc[j] += v * (float)h[j];
    }

    // slot-tree reduce: 12 -> 6 -> 3 -> 1 (data lives at lanes 5*s+g)
    #pragma unroll
    for (int j = 0; j < 8; j++) acc[j] += __shfl(acc[j], lane + 30);  // s<6 valid
    #pragma unroll
    for (int j = 0; j < 8; j++) acc[j] += __shfl(acc[j], lane + 15);  // s<3 valid
    #pragma unroll
    for (int j = 0; j < 8; j++) {
        float t1 = __shfl(acc[j], lane + 5);
        float t2 = __shfl(acc[j], lane + 10);
        acc[j] += t1 + t2;                                            // s==0 valid
    }

    // lanes 0..4 hold the 40 aggregated values (8 each); softmax via 8-lane tree
    bool act = lane < 5;
    float z[8];
    float mx = -INFINITY;
    #pragma unroll
    for (int j = 0; j < 8; j++) {
        z[j] = act ? fmaxf(acc[j], 0.f) : -INFINITY;
        mx = fmaxf(mx, z[j]);
    }
    mx = fmaxf(mx, __shfl_xor(mx, 1));
    mx = fmaxf(mx, __shfl_xor(mx, 2));
    mx = fmaxf(mx, __shfl_xor(mx, 4));

    float sm = 0.f;
    #pragma unroll
    for (int j = 0; j < 8; j++)
        sm += act ? expf(z[j] - mx) : 0.f;
    sm += __shfl_xor(sm, 1);
    sm += __shfl_xor(sm, 2);
    sm += __shfl_xor(sm, 4);

    float lse = logf(sm);
    if (act) {
        float4 o0 = {z[0]-mx-lse, z[1]-mx-lse, z[2]-mx-lse, z[3]-mx-lse};
        float4 o1 = {z[4]-mx-lse, z[5]-mx-lse, z[6]-mx-lse, z[7]-mx-lse};
        float4* dp = (float4*)(out + (size_t)r * NCLASS + g * 8);
        dp[0] = o0;
        dp[1] = o1;
    }
}

// ---------------------------------------------------------------------------
extern "C" void kernel_launch(void* const* d_in, const int* in_sizes, int n_in,
                              void* d_out, int out_size, void* d_ws, size_t ws_size,
                              hipStream_t stream) {
    const float* x     = (const float*)d_in[0];
    const int*   erow  = (const int*)d_in[1];
    const int*   ecol  = (const int*)d_in[2];
    const float* evals = (const float*)d_in[3];
    const float* W1    = (const float*)d_in[4];
    const float* W2    = (const float*)d_in[5];
    float* out = (float*)d_out;

    const int M = N_NODES;
    const int E = N_EDGES;

    char* p = (char*)d_ws;
    auto alloc = [&](size_t bytes) {
        char* q = p;
        p += (bytes + 255) & ~(size_t)255;
        return q;
    };
    int*            deg  = (int*)alloc(sizeof(int) * N_NODES);
    int*            rptr = (int*)alloc(sizeof(int) * (N_NODES + 1));
    int*            bsum = (int*)alloc(sizeof(int) * 512);
    unsigned short* ke   = (unsigned short*)alloc(sizeof(unsigned short) * N_EDGES); // 6.4 MB
    int2*           cv   = (int2*)alloc(sizeof(int2) * N_EDGES);                     // 25.6 MB
    _Float16*       W1T  = (_Float16*)alloc(sizeof(_Float16) * F_IN * HIDDEN);
    _Float16*       W2T  = (_Float16*)alloc(sizeof(_Float16) * NPAD * HIDDEN);
    _Float16*       H1   = (_Float16*)alloc(sizeof(_Float16) * (size_t)N_NODES * HIDDEN);
    _Float16*       A1   = (_Float16*)alloc(sizeof(_Float16) * (size_t)N_NODES * HIDDEN);
    _Float16*       H2   = (_Float16*)alloc(sizeof(_Float16) * (size_t)N_NODES * NCLASS);

    // --- CSR build (fill has no atomics: rank captured in hist pass) ---
    hipMemsetAsync(deg, 0, sizeof(int) * N_NODES, stream);
    hist2_kernel<<<E / 256, 256, 0, stream>>>(erow, deg, ke, E);
    scanA_kernel<<<N_SCANB, SCAN_B, 0, stream>>>(deg, rptr, bsum, N_NODES);
    scanB_kernel<<<1, 512, 0, stream>>>(bsum, N_SCANB);
    scanC_kernel<<<N_SCANB, SCAN_B, 0, stream>>>(rptr, bsum, N_NODES, E);
    fill2_kernel<<<E / 256, 256, 0, stream>>>(erow, ecol, evals, rptr, ke, cv, E);

    // --- weight conversions ---
    w1t_kernel<<<(F_IN * HIDDEN) / 256, 256, 0, stream>>>(W1, W1T);
    w2t_kernel<<<(NPAD * HIDDEN) / 256, 256, 0, stream>>>(W2, W2T);

    // --- layer 1 projection (MFMA fp16, x read once) ---
    gemm1_mfma_kernel<<<(M + 63) / 64, 256, 0, stream>>>(x, W1T, H1, M);

    // --- layer 1 aggregation + relu (gather, 2 edges/instr) ---
    spmm_h1_kernel<<<M / 4, 256, 0, stream>>>(rptr, cv, H1, A1);

    // --- layer 2 projection (MFMA) ---
    gemm2_mfma_kernel<<<(M + 63) / 64, 256, 0, stream>>>(A1, W2T, H2, M);

    // --- layer 2 aggregation + relu + log_softmax ---
    spmm40_ls_kernel<<<M / 4, 256, 0, stream>>>(rptr, cv, H2, out);
}

// Round 6
// 650.843 us; speedup vs baseline: 18.1552x; 1.0172x over previous
//
#include <hip/hip_runtime.h>
#include <math.h>

#define N_NODES 100000
#define N_EDGES 3200000
#define F_IN    512
#define HIDDEN  256
#define NCLASS  40
#define NPAD    48
#define H2STRIDE 64

#define SCAN_B  256
#define N_SCANB ((N_NODES + SCAN_B - 1) / SCAN_B)   // 391

typedef __attribute__((ext_vector_type(8))) _Float16 half8;
typedef __attribute__((ext_vector_type(4))) _Float16 half4;
typedef __attribute__((ext_vector_type(4))) float    f32x4;

// ---------------------------------------------------------------------------
// CSR build: pass 1 = histogram + per-edge rank (atomic return value)
// ---------------------------------------------------------------------------
__global__ __launch_bounds__(256) void hist2_kernel(const int* __restrict__ erow,
                                                    int* __restrict__ deg,
                                                    unsigned short* __restrict__ ke, int E) {
    int e = blockIdx.x * 256 + threadIdx.x;
    if (e < E) ke[e] = (unsigned short)atomicAdd(&deg[erow[e]], 1);
}

__global__ __launch_bounds__(256) void scanA_kernel(const int* __restrict__ deg,
                                                    int* __restrict__ rptr,
                                                    int* __restrict__ bsum, int n) {
    __shared__ int s[SCAN_B];
    int i = blockIdx.x * SCAN_B + threadIdx.x;
    int v = (i < n) ? deg[i] : 0;
    s[threadIdx.x] = v;
    __syncthreads();
    #pragma unroll
    for (int off = 1; off < SCAN_B; off <<= 1) {
        int t = (threadIdx.x >= off) ? s[threadIdx.x - off] : 0;
        __syncthreads();
        s[threadIdx.x] += t;
        __syncthreads();
    }
    if (i < n) rptr[i] = s[threadIdx.x] - v;
    if (threadIdx.x == SCAN_B - 1) bsum[blockIdx.x] = s[SCAN_B - 1];
}

__global__ __launch_bounds__(512) void scanB_kernel(int* __restrict__ bsum, int nb) {
    __shared__ int s[512];
    int t = threadIdx.x;
    int v = (t < nb) ? bsum[t] : 0;
    s[t] = v;
    __syncthreads();
    #pragma unroll
    for (int off = 1; off < 512; off <<= 1) {
        int x = (t >= off) ? s[t - off] : 0;
        __syncthreads();
        s[t] += x;
        __syncthreads();
    }
    if (t < nb) bsum[t] = s[t] - v;
}

__global__ __launch_bounds__(256) void scanC_kernel(int* __restrict__ rptr,
                                                    const int* __restrict__ bsum,
                                                    int n, int E) {
    int i = blockIdx.x * SCAN_B + threadIdx.x;
    if (i < n) rptr[i] += bsum[blockIdx.x];
    if (i == 0) rptr[n] = E;
}

// pass 2: permute (col,val) -> CSR slots, NO atomics
__global__ __launch_bounds__(256) void fill2_kernel(const int* __restrict__ erow,
                                                    const int* __restrict__ ecol,
                                                    const float* __restrict__ evals,
                                                    const int* __restrict__ rptr,
                                                    const unsigned short* __restrict__ ke,
                                                    int2* __restrict__ cv, int E) {
    int e = blockIdx.x * 256 + threadIdx.x;
    if (e < E) {
        int p = rptr[erow[e]] + ke[e];
        cv[p] = make_int2(ecol[e], __float_as_int(evals[e]));
    }
}

// ---------------------------------------------------------------------------
// Weight conversions fused: W1 -> W1T [256][512] fp16 ; W2 -> W2T [48][256] fp16
// ---------------------------------------------------------------------------
__global__ __launch_bounds__(256) void wconv_kernel(const float* __restrict__ W1,
                                                    const float* __restrict__ W2,
                                                    _Float16* __restrict__ W1T,
                                                    _Float16* __restrict__ W2T) {
    int o = blockIdx.x * 256 + threadIdx.x;   // 0..131071
    {
        int n = o >> 9, k = o & 511;
        W1T[o] = (_Float16)W1[(size_t)k * HIDDEN + n];
    }
    if (o < NPAD * HIDDEN) {                  // 0..12287
        int n = o >> 8, k = o & 255;
        W2T[o] = (n < NCLASS) ? (_Float16)W2[(size_t)k * NCLASS + n] : (_Float16)0.f;
    }
}

// ---------------------------------------------------------------------------
// GEMM1 (MFMA fp16): H1[M,256] = fp16(A[M,512]) @ fp16(W1)
// tile 64(M) x 256(N), x read once; reg-staged pipeline (load k+1 during MFMA k)
// ---------------------------------------------------------------------------
__global__ __launch_bounds__(256) void gemm1_mfma_kernel(const float* __restrict__ A,
                                                         const _Float16* __restrict__ BT,
                                                         _Float16* __restrict__ C, int M) {
    __shared__ __align__(16) char smem[33792];
    _Float16 (*As)[40]  = (_Float16 (*)[40])smem;              //  64x40  = 5120 B
    _Float16 (*Bs)[40]  = (_Float16 (*)[40])(smem + 5120);     // 256x40  = 20480 B
    _Float16 (*sC)[264] = (_Float16 (*)[264])smem;             //  64x264 = 33792 B (epilogue)

    const int t    = threadIdx.x;
    const int m0   = blockIdx.x * 64;
    const int lane = t & 63;
    const int wid  = t >> 6;
    const int wr   = wid >> 1, wc = wid & 1;
    const int lr   = lane & 15, lk = lane >> 4;

    f32x4 acc[2][8] = {};

    const int  ar   = t >> 2;            // 0..63
    const int  aq   = t & 3;             // 0..3
    const bool aval = (m0 + ar) < M;
    const float*    aptr = A  + (size_t)(m0 + ar) * F_IN + aq * 8;
    const _Float16* bptr = BT + (size_t)t * F_IN;              // row t of BT

    // prologue: load tile k0=0 into registers
    float4 a0 = {0.f,0.f,0.f,0.f}, a1 = {0.f,0.f,0.f,0.f};
    half8 b0, b1, b2, b3;
    if (aval) { a0 = *(const float4*)(aptr); a1 = *(const float4*)(aptr + 4); }
    { const half8* bp = (const half8*)(bptr); b0 = bp[0]; b1 = bp[1]; b2 = bp[2]; b3 = bp[3]; }

    for (int k0 = 0; k0 < F_IN; k0 += 32) {
        // commit staged registers to LDS
        half8 ah;
        ah[0]=(_Float16)a0.x; ah[1]=(_Float16)a0.y; ah[2]=(_Float16)a0.z; ah[3]=(_Float16)a0.w;
        ah[4]=(_Float16)a1.x; ah[5]=(_Float16)a1.y; ah[6]=(_Float16)a1.z; ah[7]=(_Float16)a1.w;
        *(half8*)&As[ar][aq * 8] = ah;
        *(half8*)&Bs[t][0]  = b0;
        *(half8*)&Bs[t][8]  = b1;
        *(half8*)&Bs[t][16] = b2;
        *(half8*)&Bs[t][24] = b3;
        __syncthreads();

        // prefetch next tile (consumed after MFMAs, overlaps with compute)
        if (k0 + 32 < F_IN) {
            if (aval) {
                a0 = *(const float4*)(aptr + k0 + 32);
                a1 = *(const float4*)(aptr + k0 + 36);
            }
            const half8* bp = (const half8*)(bptr + k0 + 32);
            b0 = bp[0]; b1 = bp[1]; b2 = bp[2]; b3 = bp[3];
        }

        half8 af0 = *(half8*)&As[wr * 32 + lr][lk * 8];
        half8 af1 = *(half8*)&As[wr * 32 + 16 + lr][lk * 8];
        #pragma unroll
        for (int fn = 0; fn < 8; fn++) {
            half8 bf = *(half8*)&Bs[wc * 128 + fn * 16 + lr][lk * 8];
            acc[0][fn] = __builtin_amdgcn_mfma_f32_16x16x32_f16(af0, bf, acc[0][fn], 0, 0, 0);
            acc[1][fn] = __builtin_amdgcn_mfma_f32_16x16x32_f16(af1, bf, acc[1][fn], 0, 0, 0);
        }
        __syncthreads();
    }

    #pragma unroll
    for (int fm = 0; fm < 2; fm++)
        #pragma unroll
        for (int fn = 0; fn < 8; fn++)
            #pragma unroll
            for (int j = 0; j < 4; j++) {
                int row = wr * 32 + fm * 16 + lk * 4 + j;
                int col = wc * 128 + fn * 16 + lr;
                sC[row][col] = (_Float16)acc[fm][fn][j];
            }
    __syncthreads();

    int m = m0 + ar;
    if (m < M) {
        const float4* sp = (const float4*)&sC[ar][aq * 64];
        float4*       dp = (float4*)(C + (size_t)m * HIDDEN + aq * 64);
        #pragma unroll
        for (int j = 0; j < 8; j++) dp[j] = sp[j];
    }
}

// ---------------------------------------------------------------------------
// SpMM gather D=256 (fp16) + ReLU. One wave per row; 2 edges per gather
// instruction, 8 gathers (16 edges) in flight per wave.
// ---------------------------------------------------------------------------
__global__ __launch_bounds__(256) void spmm_h1_kernel(const int* __restrict__ rptr,
                                                      const int2* __restrict__ cv,
                                                      const _Float16* __restrict__ H1,
                                                      _Float16* __restrict__ A1) {
    int t = threadIdx.x, wave = t >> 6, lane = t & 63;
    int r = blockIdx.x * 4 + wave;
    int e0 = rptr[r], e1 = rptr[r + 1];
    int hf = lane >> 5;            // 0/1: which edge of the pair
    int fl = lane & 31;            // feature block (8 fp16 each)

    float acc[8] = {};

    for (int e = e0; e < e1; e += 16) {
        #pragma unroll
        for (int u = 0; u < 8; u++) {
            int idx = e + 2 * u + hf;
            bool ok = idx < e1;
            int2 p = cv[ok ? idx : e0];
            float v = ok ? __int_as_float(p.y) : 0.f;
            half8 h = *(const half8*)(H1 + (size_t)p.x * HIDDEN + fl * 8);
            #pragma unroll
            for (int j = 0; j < 8; j++)
                acc[j] += v * (float)h[j];
        }
    }

    // merge the two half-wave edge groups
    #pragma unroll
    for (int j = 0; j < 8; j++)
        acc[j] += __shfl_xor(acc[j], 32);

    if (hf == 0) {
        half8 o;
        #pragma unroll
        for (int j = 0; j < 8; j++) o[j] = (_Float16)fmaxf(acc[j], 0.f);
        *(half8*)(A1 + (size_t)r * HIDDEN + fl * 8) = o;
    }
}

// ---------------------------------------------------------------------------
// GEMM2 (MFMA fp16): H2[M, pad64] = A1[M,256] @ W2 ; tile 64(M) x 48(N)
// ---------------------------------------------------------------------------
__global__ __launch_bounds__(256) void gemm2_mfma_kernel(const _Float16* __restrict__ A1,
                                                         const _Float16* __restrict__ W2T,
                                                         _Float16* __restrict__ H2, int M) {
    __shared__ _Float16 As[64][264];   // 33792 B
    __shared__ _Float16 Bs[48][264];   // 25344 B

    const int t    = threadIdx.x;
    const int m0   = blockIdx.x * 64;
    const int lane = t & 63;
    const int wid  = t >> 6;
    const int lr   = lane & 15, lk = lane >> 4;

    #pragma unroll
    for (int i = 0; i < 6; i++) {
        int idx = t + i * 256;          // 0..1535
        int row = idx >> 5, c8 = idx & 31;
        *(half8*)&Bs[row][c8 * 8] = *(const half8*)(W2T + (size_t)row * HIDDEN + c8 * 8);
    }
    {
        int ar = t >> 2, aq = t & 3;
        bool aval = (m0 + ar) < M;
        #pragma unroll
        for (int j = 0; j < 8; j++) {
            half8 v = aval ? *(const half8*)(A1 + (size_t)(m0 + ar) * HIDDEN + aq * 64 + j * 8)
                           : (half8)(_Float16)0.f;
            *(half8*)&As[ar][aq * 64 + j * 8] = v;
        }
    }
    __syncthreads();

    f32x4 acc[3] = {};
    #pragma unroll
    for (int ks = 0; ks < 8; ks++) {
        half8 af = *(half8*)&As[wid * 16 + lr][ks * 32 + lk * 8];
        #pragma unroll
        for (int fn = 0; fn < 3; fn++) {
            half8 bf = *(half8*)&Bs[fn * 16 + lr][ks * 32 + lk * 8];
            acc[fn] = __builtin_amdgcn_mfma_f32_16x16x32_f16(af, bf, acc[fn], 0, 0, 0);
        }
    }

    #pragma unroll
    for (int fn = 0; fn < 3; fn++)
        #pragma unroll
        for (int j = 0; j < 4; j++) {
            int row = wid * 16 + lk * 4 + j;
            int col = fn * 16 + lr;     // 0..47, within the 64 stride
            int m = m0 + row;
            if (m < M)
                H2[(size_t)m * H2STRIDE + col] = (_Float16)acc[fn][j];
        }
}

// ---------------------------------------------------------------------------
// SpMM gather D=40 (fp16, stride-64 rows = one 128B line/edge) + ReLU +
// log_softmax. One wave per row; 12 edges/iter, 5 lanes x half8 per edge.
// ---------------------------------------------------------------------------
__global__ __launch_bounds__(256) void spmm40_ls_kernel(const int* __restrict__ rptr,
                                                        const int2* __restrict__ cv,
                                                        const _Float16* __restrict__ H2,
                                                        float* __restrict__ out) {
    int t = threadIdx.x;
    int wave = t >> 6, lane = t & 63;
    int r = blockIdx.x * 4 + wave;

    int e0 = rptr[r], e1 = rptr[r + 1];
    int s = lane / 5;           // edge slot 0..11 (lane 60..63 -> s=12, inactive)
    int g = lane % 5;           // feature block: classes g*8 .. g*8+7
    bool lact = lane < 60;

    float acc[8] = {};
    for (int e = e0; e < e1; e += 12) {
        int idx = e + s;
        bool ok = lact && (idx < e1);
        int2 p = cv[ok ? idx : e0];
        float v = ok ? __int_as_float(p.y) : 0.f;
        half8 h = *(const half8*)(H2 + (size_t)p.x * H2STRIDE + g * 8);
        #pragma unroll
        for (int j = 0; j < 8; j++)
            acc[j] += v * (float)h[j];
    }

    // slot-tree reduce: 12 -> 6 -> 3 -> 1 (data lives at lanes 5*s+g)
    #pragma unroll
    for (int j = 0; j < 8; j++) acc[j] += __shfl(acc[j], lane + 30);  // s<6 valid
    #pragma unroll
    for (int j = 0; j < 8; j++) acc[j] += __shfl(acc[j], lane + 15);  // s<3 valid
    #pragma unroll
    for (int j = 0; j < 8; j++) {
        float t1 = __shfl(acc[j], lane + 5);
        float t2 = __shfl(acc[j], lane + 10);
        acc[j] += t1 + t2;                                            // s==0 valid
    }

    // lanes 0..4 hold the 40 aggregated values (8 each); softmax via 8-lane tree
    bool act = lane < 5;
    float z[8];
    float mx = -INFINITY;
    #pragma unroll
    for (int j = 0; j < 8; j++) {
        z[j] = act ? fmaxf(acc[j], 0.f) : -INFINITY;
        mx = fmaxf(mx, z[j]);
    }
    mx = fmaxf(mx, __shfl_xor(mx, 1));
    mx = fmaxf(mx, __shfl_xor(mx, 2));
    mx = fmaxf(mx, __shfl_xor(mx, 4));

    float sm = 0.f;
    #pragma unroll
    for (int j = 0; j < 8; j++)
        sm += act ? expf(z[j] - mx) : 0.f;
    sm += __shfl_xor(sm, 1);
    sm += __shfl_xor(sm, 2);
    sm += __shfl_xor(sm, 4);

    float lse = logf(sm);
    if (act) {
        float4 o0 = {z[0]-mx-lse, z[1]-mx-lse, z[2]-mx-lse, z[3]-mx-lse};
        float4 o1 = {z[4]-mx-lse, z[5]-mx-lse, z[6]-mx-lse, z[7]-mx-lse};
        float4* dp = (float4*)(out + (size_t)r * NCLASS + g * 8);
        dp[0] = o0;
        dp[1] = o1;
    }
}

// ---------------------------------------------------------------------------
extern "C" void kernel_launch(void* const* d_in, const int* in_sizes, int n_in,
                              void* d_out, int out_size, void* d_ws, size_t ws_size,
                              hipStream_t stream) {
    const float* x     = (const float*)d_in[0];
    const int*   erow  = (const int*)d_in[1];
    const int*   ecol  = (const int*)d_in[2];
    const float* evals = (const float*)d_in[3];
    const float* W1    = (const float*)d_in[4];
    const float* W2    = (const float*)d_in[5];
    float* out = (float*)d_out;

    const int M = N_NODES;
    const int E = N_EDGES;

    char* p = (char*)d_ws;
    auto alloc = [&](size_t bytes) {
        char* q = p;
        p += (bytes + 255) & ~(size_t)255;
        return q;
    };
    int*            deg  = (int*)alloc(sizeof(int) * N_NODES);
    int*            rptr = (int*)alloc(sizeof(int) * (N_NODES + 1));
    int*            bsum = (int*)alloc(sizeof(int) * 512);
    unsigned short* ke   = (unsigned short*)alloc(sizeof(unsigned short) * N_EDGES); // 6.4 MB
    int2*           cv   = (int2*)alloc(sizeof(int2) * N_EDGES);                     // 25.6 MB
    _Float16*       W1T  = (_Float16*)alloc(sizeof(_Float16) * F_IN * HIDDEN);
    _Float16*       W2T  = (_Float16*)alloc(sizeof(_Float16) * NPAD * HIDDEN);
    _Float16*       H1   = (_Float16*)alloc(sizeof(_Float16) * (size_t)N_NODES * HIDDEN); // 51.2 MB
    _Float16*       A1   = (_Float16*)alloc(sizeof(_Float16) * (size_t)N_NODES * HIDDEN); // 51.2 MB
    _Float16*       H2   = H1;   // H1 is dead once gemm2 runs; reuse (12.8 MB)

    // --- CSR build (fill has no atomics: rank captured in hist pass) ---
    hipMemsetAsync(deg, 0, sizeof(int) * N_NODES, stream);
    hist2_kernel<<<E / 256, 256, 0, stream>>>(erow, deg, ke, E);
    scanA_kernel<<<N_SCANB, SCAN_B, 0, stream>>>(deg, rptr, bsum, N_NODES);
    scanB_kernel<<<1, 512, 0, stream>>>(bsum, N_SCANB);
    scanC_kernel<<<N_SCANB, SCAN_B, 0, stream>>>(rptr, bsum, N_NODES, E);
    fill2_kernel<<<E / 256, 256, 0, stream>>>(erow, ecol, evals, rptr, ke, cv, E);

    // --- weight conversions (one launch) ---
    wconv_kernel<<<(F_IN * HIDDEN) / 256, 256, 0, stream>>>(W1, W2, W1T, W2T);

    // --- layer 1 projection (MFMA fp16, x read once, reg-staged pipeline) ---
    gemm1_mfma_kernel<<<(M + 63) / 64, 256, 0, stream>>>(x, W1T, H1, M);

    // --- layer 1 aggregation + relu (gather, 8 loads in flight) ---
    spmm_h1_kernel<<<M / 4, 256, 0, stream>>>(rptr, cv, H1, A1);

    // --- layer 2 projection (MFMA, padded-stride output) ---
    gemm2_mfma_kernel<<<(M + 63) / 64, 256, 0, stream>>>(A1, W2T, H2, M);

    // --- layer 2 aggregation + relu + log_softmax ---
    spmm40_ls_kernel<<<M / 4, 256, 0, stream>>>(rptr, cv, H2, out);
}

// Round 7
// 623.865 us; speedup vs baseline: 18.9403x; 1.0432x over previous
//
#include <hip/hip_runtime.h>
#include <math.h>

#define N_NODES 100000
#define N_EDGES 3200000
#define F_IN    512
#define HIDDEN  256
#define NCLASS  40
#define NPAD    48
#define H2STRIDE 64
#define FB_ROWS 8

#define SCAN_B  256
#define N_SCANB ((N_NODES + SCAN_B - 1) / SCAN_B)   // 391

typedef __attribute__((ext_vector_type(8))) _Float16 half8;
typedef __attribute__((ext_vector_type(4))) _Float16 half4;
typedef __attribute__((ext_vector_type(4))) float    f32x4;

// ---------------------------------------------------------------------------
// CSR build: pass 1 = histogram + per-edge rank (atomic return value)
// ---------------------------------------------------------------------------
__global__ __launch_bounds__(256) void hist2_kernel(const int* __restrict__ erow,
                                                    int* __restrict__ deg,
                                                    unsigned short* __restrict__ ke, int E) {
    int e = blockIdx.x * 256 + threadIdx.x;
    if (e < E) ke[e] = (unsigned short)atomicAdd(&deg[erow[e]], 1);
}

__global__ __launch_bounds__(256) void scanA_kernel(const int* __restrict__ deg,
                                                    int* __restrict__ rptr,
                                                    int* __restrict__ bsum, int n) {
    __shared__ int s[SCAN_B];
    int i = blockIdx.x * SCAN_B + threadIdx.x;
    int v = (i < n) ? deg[i] : 0;
    s[threadIdx.x] = v;
    __syncthreads();
    #pragma unroll
    for (int off = 1; off < SCAN_B; off <<= 1) {
        int t = (threadIdx.x >= off) ? s[threadIdx.x - off] : 0;
        __syncthreads();
        s[threadIdx.x] += t;
        __syncthreads();
    }
    if (i < n) rptr[i] = s[threadIdx.x] - v;
    if (threadIdx.x == SCAN_B - 1) bsum[blockIdx.x] = s[SCAN_B - 1];
}

__global__ __launch_bounds__(512) void scanB_kernel(int* __restrict__ bsum, int nb) {
    __shared__ int s[512];
    int t = threadIdx.x;
    int v = (t < nb) ? bsum[t] : 0;
    s[t] = v;
    __syncthreads();
    #pragma unroll
    for (int off = 1; off < 512; off <<= 1) {
        int x = (t >= off) ? s[t - off] : 0;
        __syncthreads();
        s[t] += x;
        __syncthreads();
    }
    if (t < nb) bsum[t] = s[t] - v;
}

__global__ __launch_bounds__(256) void scanC_kernel(int* __restrict__ rptr,
                                                    const int* __restrict__ bsum,
                                                    int n, int E) {
    int i = blockIdx.x * SCAN_B + threadIdx.x;
    if (i < n) rptr[i] += bsum[blockIdx.x];
    if (i == 0) rptr[n] = E;
}

// pass 2: permute (col,val) -> CSR slots, NO atomics
__global__ __launch_bounds__(256) void fill2_kernel(const int* __restrict__ erow,
                                                    const int* __restrict__ ecol,
                                                    const float* __restrict__ evals,
                                                    const int* __restrict__ rptr,
                                                    const unsigned short* __restrict__ ke,
                                                    int2* __restrict__ cv, int E) {
    int e = blockIdx.x * 256 + threadIdx.x;
    if (e < E) {
        int p = rptr[erow[e]] + ke[e];
        cv[p] = make_int2(ecol[e], __float_as_int(evals[e]));
    }
}

// ---------------------------------------------------------------------------
// Weight conversions fused: W1 -> W1T [256][512] fp16 ; W2 -> W2T [48][256] fp16
// ---------------------------------------------------------------------------
__global__ __launch_bounds__(256) void wconv_kernel(const float* __restrict__ W1,
                                                    const float* __restrict__ W2,
                                                    _Float16* __restrict__ W1T,
                                                    _Float16* __restrict__ W2T) {
    int o = blockIdx.x * 256 + threadIdx.x;   // 0..131071
    {
        int n = o >> 9, k = o & 511;
        W1T[o] = (_Float16)W1[(size_t)k * HIDDEN + n];
    }
    if (o < NPAD * HIDDEN) {                  // 0..12287
        int n = o >> 8, k = o & 255;
        W2T[o] = (n < NCLASS) ? (_Float16)W2[(size_t)k * NCLASS + n] : (_Float16)0.f;
    }
}

// ---------------------------------------------------------------------------
// GEMM1 (MFMA fp16): H1[M,256] = fp16(A[M,512]) @ fp16(W1)
// tile 64(M) x 256(N), x read once; 4 waves each with a 64x64 wave tile
// (4x4 fragments -> 8 ds_reads per 16 MFMAs); reg-staged prefetch pipeline.
// ---------------------------------------------------------------------------
__global__ __launch_bounds__(256) void gemm1_mfma_kernel(const float* __restrict__ A,
                                                         const _Float16* __restrict__ BT,
                                                         _Float16* __restrict__ C, int M) {
    __shared__ __align__(16) char smem[33792];
    _Float16 (*As)[40]  = (_Float16 (*)[40])smem;              //  64x40  = 5120 B
    _Float16 (*Bs)[40]  = (_Float16 (*)[40])(smem + 5120);     // 256x40  = 20480 B
    _Float16 (*sC)[264] = (_Float16 (*)[264])smem;             //  64x264 = 33792 B (epilogue)

    const int t    = threadIdx.x;
    const int m0   = blockIdx.x * 64;
    const int lane = t & 63;
    const int wid  = t >> 6;
    const int lr   = lane & 15, lk = lane >> 4;

    f32x4 acc[4][4] = {};

    const int  ar   = t >> 2;            // 0..63
    const int  aq   = t & 3;             // 0..3
    const bool aval = (m0 + ar) < M;
    const float*    aptr = A  + (size_t)(m0 + ar) * F_IN + aq * 8;
    const _Float16* bptr = BT + (size_t)t * F_IN;              // row t of BT

    // prologue: load tile k0=0 into registers
    float4 a0 = {0.f,0.f,0.f,0.f}, a1 = {0.f,0.f,0.f,0.f};
    half8 b0, b1, b2, b3;
    if (aval) { a0 = *(const float4*)(aptr); a1 = *(const float4*)(aptr + 4); }
    { const half8* bp = (const half8*)(bptr); b0 = bp[0]; b1 = bp[1]; b2 = bp[2]; b3 = bp[3]; }

    for (int k0 = 0; k0 < F_IN; k0 += 32) {
        // commit staged registers to LDS
        half8 ah;
        ah[0]=(_Float16)a0.x; ah[1]=(_Float16)a0.y; ah[2]=(_Float16)a0.z; ah[3]=(_Float16)a0.w;
        ah[4]=(_Float16)a1.x; ah[5]=(_Float16)a1.y; ah[6]=(_Float16)a1.z; ah[7]=(_Float16)a1.w;
        *(half8*)&As[ar][aq * 8] = ah;
        *(half8*)&Bs[t][0]  = b0;
        *(half8*)&Bs[t][8]  = b1;
        *(half8*)&Bs[t][16] = b2;
        *(half8*)&Bs[t][24] = b3;
        __syncthreads();

        // prefetch next tile (consumed after MFMAs, overlaps with compute)
        if (k0 + 32 < F_IN) {
            if (aval) {
                a0 = *(const float4*)(aptr + k0 + 32);
                a1 = *(const float4*)(aptr + k0 + 36);
            }
            const half8* bp = (const half8*)(bptr + k0 + 32);
            b0 = bp[0]; b1 = bp[1]; b2 = bp[2]; b3 = bp[3];
        }

        half8 af[4], bf[4];
        #pragma unroll
        for (int fm = 0; fm < 4; fm++) af[fm] = *(half8*)&As[fm * 16 + lr][lk * 8];
        #pragma unroll
        for (int fn = 0; fn < 4; fn++) bf[fn] = *(half8*)&Bs[wid * 64 + fn * 16 + lr][lk * 8];
        #pragma unroll
        for (int fm = 0; fm < 4; fm++)
            #pragma unroll
            for (int fn = 0; fn < 4; fn++)
                acc[fm][fn] = __builtin_amdgcn_mfma_f32_16x16x32_f16(af[fm], bf[fn], acc[fm][fn], 0, 0, 0);
        __syncthreads();
    }

    // epilogue: acc -> LDS (fp16) -> coalesced global stores
    #pragma unroll
    for (int fm = 0; fm < 4; fm++)
        #pragma unroll
        for (int fn = 0; fn < 4; fn++)
            #pragma unroll
            for (int j = 0; j < 4; j++) {
                int row = fm * 16 + lk * 4 + j;
                int col = wid * 64 + fn * 16 + lr;
                sC[row][col] = (_Float16)acc[fm][fn][j];
            }
    __syncthreads();

    int m = m0 + ar;
    if (m < M) {
        const float4* sp = (const float4*)&sC[ar][aq * 64];
        float4*       dp = (float4*)(C + (size_t)m * HIDDEN + aq * 64);
        #pragma unroll
        for (int j = 0; j < 8; j++) dp[j] = sp[j];
    }
}

// ---------------------------------------------------------------------------
// FUSED: SpMM gather D=256 (fp16) + ReLU + GEMM2 (@W2 via MFMA epilogue).
// 512 threads = 8 waves = 8 rows; gathered rows staged in LDS; one barrier;
// wave 0 computes H2[8 rows][48] with 24 MFMAs (rows 8..15 zero-padded).
// ---------------------------------------------------------------------------
__global__ __launch_bounds__(512) void spmm_gemm2_kernel(const int* __restrict__ rptr,
                                                         const int2* __restrict__ cv,
                                                         const _Float16* __restrict__ H1,
                                                         const _Float16* __restrict__ W2T,
                                                         _Float16* __restrict__ H2) {
    __shared__ _Float16 sW2[NPAD][264];     // 25344 B
    __shared__ _Float16 sRow[16][264];      //  8448 B

    int t = threadIdx.x;
    int wave = t >> 6, lane = t & 63;
    int m0 = blockIdx.x * FB_ROWS;
    int r = m0 + wave;

    // stage W2T (48x256) : 3 half8 per thread
    #pragma unroll
    for (int i = 0; i < 3; i++) {
        int idx = t + i * 512;              // 0..1535
        int row = idx >> 5, c8 = idx & 31;
        *(half8*)&sW2[row][c8 * 8] = *(const half8*)(W2T + (size_t)row * HIDDEN + c8 * 8);
    }
    // zero pad rows 8..15 of sRow
    if (t < 256) {
        int row = 8 + (t >> 5), c8 = t & 31;
        *(half8*)&sRow[row][c8 * 8] = (half8)(_Float16)0.f;
    }

    // gather: 2 edges per instr (32 lanes x 16B cover one 512B row), 8 edges/iter
    int e0 = rptr[r], e1 = rptr[r + 1];
    int hf = lane >> 5;
    int fl = lane & 31;

    float acc[8] = {};
    for (int e = e0; e < e1; e += 8) {
        #pragma unroll
        for (int u = 0; u < 4; u++) {
            int idx = e + 2 * u + hf;
            bool ok = idx < e1;
            int2 p = cv[ok ? idx : e0];
            float v = ok ? __int_as_float(p.y) : 0.f;
            half8 h = *(const half8*)(H1 + (size_t)p.x * HIDDEN + fl * 8);
            #pragma unroll
            for (int j = 0; j < 8; j++)
                acc[j] += v * (float)h[j];
        }
    }
    #pragma unroll
    for (int j = 0; j < 8; j++)
        acc[j] += __shfl_xor(acc[j], 32);

    if (hf == 0) {
        half8 o;
        #pragma unroll
        for (int j = 0; j < 8; j++) o[j] = (_Float16)fmaxf(acc[j], 0.f);
        *(half8*)&sRow[wave][fl * 8] = o;
    }
    __syncthreads();

    // MFMA epilogue on wave 0: [16(8 real)x256] @ [48x256]^T
    if (wave == 0) {
        int lr = lane & 15, lk = lane >> 4;
        f32x4 acc2[3] = {};
        #pragma unroll
        for (int ks = 0; ks < 8; ks++) {
            half8 af = *(half8*)&sRow[lr][ks * 32 + lk * 8];
            #pragma unroll
            for (int fn = 0; fn < 3; fn++) {
                half8 bf = *(half8*)&sW2[fn * 16 + lr][ks * 32 + lk * 8];
                acc2[fn] = __builtin_amdgcn_mfma_f32_16x16x32_f16(af, bf, acc2[fn], 0, 0, 0);
            }
        }
        #pragma unroll
        for (int fn = 0; fn < 3; fn++)
            #pragma unroll
            for (int j = 0; j < 4; j++) {
                int row = lk * 4 + j;       // 0..15, rows 8..15 are pad
                int col = fn * 16 + lr;     // 0..47
                if (row < FB_ROWS)
                    H2[(size_t)(m0 + row) * H2STRIDE + col] = (_Float16)acc2[fn][j];
            }
    }
}

// ---------------------------------------------------------------------------
// SpMM gather D=40 (fp16, stride-64 rows = one 128B line/edge) + ReLU +
// log_softmax. One wave per row; 24 edges/iter (2 independent loads in flight).
// ---------------------------------------------------------------------------
__global__ __launch_bounds__(256) void spmm40_ls_kernel(const int* __restrict__ rptr,
                                                        const int2* __restrict__ cv,
                                                        const _Float16* __restrict__ H2,
                                                        float* __restrict__ out) {
    int t = threadIdx.x;
    int wave = t >> 6, lane = t & 63;
    int r = blockIdx.x * 4 + wave;

    int e0 = rptr[r], e1 = rptr[r + 1];
    int s = lane / 5;           // edge slot 0..11 (lane 60..63 -> s=12, inactive)
    int g = lane % 5;           // feature block: classes g*8 .. g*8+7
    bool lact = lane < 60;

    float acc[8] = {};
    for (int e = e0; e < e1; e += 24) {
        int idx0 = e + s, idx1 = e + 12 + s;
        bool ok0 = lact && (idx0 < e1);
        bool ok1 = lact && (idx1 < e1);
        int2 p0 = cv[ok0 ? idx0 : e0];
        int2 p1 = cv[ok1 ? idx1 : e0];
        float v0 = ok0 ? __int_as_float(p0.y) : 0.f;
        float v1 = ok1 ? __int_as_float(p1.y) : 0.f;
        half8 h0 = *(const half8*)(H2 + (size_t)p0.x * H2STRIDE + g * 8);
        half8 h1 = *(const half8*)(H2 + (size_t)p1.x * H2STRIDE + g * 8);
        #pragma unroll
        for (int j = 0; j < 8; j++)
            acc[j] += v0 * (float)h0[j] + v1 * (float)h1[j];
    }

    // slot-tree reduce: 12 -> 6 -> 3 -> 1 (data lives at lanes 5*s+g)
    #pragma unroll
    for (int j = 0; j < 8; j++) acc[j] += __shfl(acc[j], lane + 30);  // s<6 valid
    #pragma unroll
    for (int j = 0; j < 8; j++) acc[j] += __shfl(acc[j], lane + 15);  // s<3 valid
    #pragma unroll
    for (int j = 0; j < 8; j++) {
        float t1 = __shfl(acc[j], lane + 5);
        float t2 = __shfl(acc[j], lane + 10);
        acc[j] += t1 + t2;                                            // s==0 valid
    }

    // lanes 0..4 hold the 40 aggregated values (8 each); softmax via 8-lane tree
    bool act = lane < 5;
    float z[8];
    float mx = -INFINITY;
    #pragma unroll
    for (int j = 0; j < 8; j++) {
        z[j] = act ? fmaxf(acc[j], 0.f) : -INFINITY;
        mx = fmaxf(mx, z[j]);
    }
    mx = fmaxf(mx, __shfl_xor(mx, 1));
    mx = fmaxf(mx, __shfl_xor(mx, 2));
    mx = fmaxf(mx, __shfl_xor(mx, 4));

    float sm = 0.f;
    #pragma unroll
    for (int j = 0; j < 8; j++)
        sm += act ? expf(z[j] - mx) : 0.f;
    sm += __shfl_xor(sm, 1);
    sm += __shfl_xor(sm, 2);
    sm += __shfl_xor(sm, 4);

    float lse = logf(sm);
    if (act) {
        float4 o0 = {z[0]-mx-lse, z[1]-mx-lse, z[2]-mx-lse, z[3]-mx-lse};
        float4 o1 = {z[4]-mx-lse, z[5]-mx-lse, z[6]-mx-lse, z[7]-mx-lse};
        float4* dp = (float4*)(out + (size_t)r * NCLASS + g * 8);
        dp[0] = o0;
        dp[1] = o1;
    }
}

// ---------------------------------------------------------------------------
extern "C" void kernel_launch(void* const* d_in, const int* in_sizes, int n_in,
                              void* d_out, int out_size, void* d_ws, size_t ws_size,
                              hipStream_t stream) {
    const float* x     = (const float*)d_in[0];
    const int*   erow  = (const int*)d_in[1];
    const int*   ecol  = (const int*)d_in[2];
    const float* evals = (const float*)d_in[3];
    const float* W1    = (const float*)d_in[4];
    const float* W2    = (const float*)d_in[5];
    float* out = (float*)d_out;

    const int M = N_NODES;
    const int E = N_EDGES;

    char* p = (char*)d_ws;
    auto alloc = [&](size_t bytes) {
        char* q = p;
        p += (bytes + 255) & ~(size_t)255;
        return q;
    };
    int*            deg  = (int*)alloc(sizeof(int) * N_NODES);
    int*            rptr = (int*)alloc(sizeof(int) * (N_NODES + 1));
    int*            bsum = (int*)alloc(sizeof(int) * 512);
    unsigned short* ke   = (unsigned short*)alloc(sizeof(unsigned short) * N_EDGES); // 6.4 MB
    int2*           cv   = (int2*)alloc(sizeof(int2) * N_EDGES);                     // 25.6 MB
    _Float16*       W1T  = (_Float16*)alloc(sizeof(_Float16) * F_IN * HIDDEN);
    _Float16*       W2T  = (_Float16*)alloc(sizeof(_Float16) * NPAD * HIDDEN);
    _Float16*       H1   = (_Float16*)alloc(sizeof(_Float16) * (size_t)N_NODES * HIDDEN);   // 51.2 MB
    _Float16*       H2   = (_Float16*)alloc(sizeof(_Float16) * (size_t)N_NODES * H2STRIDE); // 12.8 MB

    // --- CSR build (fill has no atomics: rank captured in hist pass) ---
    hipMemsetAsync(deg, 0, sizeof(int) * N_NODES, stream);
    hist2_kernel<<<E / 256, 256, 0, stream>>>(erow, deg, ke, E);
    scanA_kernel<<<N_SCANB, SCAN_B, 0, stream>>>(deg, rptr, bsum, N_NODES);
    scanB_kernel<<<1, 512, 0, stream>>>(bsum, N_SCANB);
    scanC_kernel<<<N_SCANB, SCAN_B, 0, stream>>>(rptr, bsum, N_NODES, E);
    fill2_kernel<<<E / 256, 256, 0, stream>>>(erow, ecol, evals, rptr, ke, cv, E);

    // --- weight conversions (one launch) ---
    wconv_kernel<<<(F_IN * HIDDEN) / 256, 256, 0, stream>>>(W1, W2, W1T, W2T);

    // --- layer 1 projection (MFMA fp16, x read once, reg-staged pipeline) ---
    gemm1_mfma_kernel<<<(M + 63) / 64, 256, 0, stream>>>(x, W1T, H1, M);

    // --- fused: layer-1 aggregation + relu + @W2 (MFMA epilogue) ---
    spmm_gemm2_kernel<<<M / FB_ROWS, 512, 0, stream>>>(rptr, cv, H1, W2T, H2);

    // --- layer 2 aggregation + relu + log_softmax ---
    spmm40_ls_kernel<<<M / 4, 256, 0, stream>>>(rptr, cv, H2, out);
}

// Round 8
// 599.506 us; speedup vs baseline: 19.7098x; 1.0406x over previous
//
#include <hip/hip_runtime.h>
#include <math.h>

#define N_NODES 100000
#define N_EDGES 3200000
#define F_IN    512
#define HIDDEN  256
#define NCLASS  40
#define NPAD    48
#define H2STRIDE 64
#define FB_ROWS 16
#define G1_BLOCKS ((N_NODES + 63) / 64)          // 1563
#define FILL_BLOCKS (N_EDGES / 256)              // 12500

#define SCAN_B  256
#define N_SCANB ((N_NODES + SCAN_B - 1) / SCAN_B)   // 391

typedef __attribute__((ext_vector_type(8))) _Float16 half8;
typedef __attribute__((ext_vector_type(4))) _Float16 half4;
typedef __attribute__((ext_vector_type(4))) float    f32x4;

// ---------------------------------------------------------------------------
// init: deg = 0  +  W1 -> W1T [256][512] fp16  +  W2 -> W2T [48][256] fp16
// ---------------------------------------------------------------------------
__global__ __launch_bounds__(256) void init_kernel(const float* __restrict__ W1,
                                                   const float* __restrict__ W2,
                                                   _Float16* __restrict__ W1T,
                                                   _Float16* __restrict__ W2T,
                                                   int* __restrict__ deg) {
    int o = blockIdx.x * 256 + threadIdx.x;   // 0..131071
    {
        int n = o >> 9, k = o & 511;
        W1T[o] = (_Float16)W1[(size_t)k * HIDDEN + n];
    }
    if (o < NPAD * HIDDEN) {                  // 0..12287
        int n = o >> 8, k = o & 255;
        W2T[o] = (n < NCLASS) ? (_Float16)W2[(size_t)k * NCLASS + n] : (_Float16)0.f;
    }
    if (o < N_NODES) deg[o] = 0;
}

// ---------------------------------------------------------------------------
// CSR build: pass 1 = histogram + per-edge rank (atomic return value)
// ---------------------------------------------------------------------------
__global__ __launch_bounds__(256) void hist2_kernel(const int* __restrict__ erow,
                                                    int* __restrict__ deg,
                                                    unsigned short* __restrict__ ke, int E) {
    int e = blockIdx.x * 256 + threadIdx.x;
    if (e < E) ke[e] = (unsigned short)atomicAdd(&deg[erow[e]], 1);
}

__global__ __launch_bounds__(256) void scanA_kernel(const int* __restrict__ deg,
                                                    int* __restrict__ rptr,
                                                    int* __restrict__ bsum, int n) {
    __shared__ int s[SCAN_B];
    int i = blockIdx.x * SCAN_B + threadIdx.x;
    int v = (i < n) ? deg[i] : 0;
    s[threadIdx.x] = v;
    __syncthreads();
    #pragma unroll
    for (int off = 1; off < SCAN_B; off <<= 1) {
        int t = (threadIdx.x >= off) ? s[threadIdx.x - off] : 0;
        __syncthreads();
        s[threadIdx.x] += t;
        __syncthreads();
    }
    if (i < n) rptr[i] = s[threadIdx.x] - v;
    if (threadIdx.x == SCAN_B - 1) bsum[blockIdx.x] = s[SCAN_B - 1];
}

__global__ __launch_bounds__(512) void scanB_kernel(int* __restrict__ bsum, int nb) {
    __shared__ int s[512];
    int t = threadIdx.x;
    int v = (t < nb) ? bsum[t] : 0;
    s[t] = v;
    __syncthreads();
    #pragma unroll
    for (int off = 1; off < 512; off <<= 1) {
        int x = (t >= off) ? s[t - off] : 0;
        __syncthreads();
        s[t] += x;
        __syncthreads();
    }
    if (t < nb) bsum[t] = s[t] - v;
}

__global__ __launch_bounds__(256) void scanC_kernel(int* __restrict__ rptr,
                                                    const int* __restrict__ bsum,
                                                    int n, int E) {
    int i = blockIdx.x * SCAN_B + threadIdx.x;
    if (i < n) rptr[i] += bsum[blockIdx.x];
    if (i == 0) rptr[n] = E;
}

// ---------------------------------------------------------------------------
// MERGED: blocks [0, G1_BLOCKS) = GEMM1 ; blocks [G1_BLOCKS, +FILL_BLOCKS) = fill
// (independent work: gemm1 needs W1T/x only; fill needs scans only)
// ---------------------------------------------------------------------------
__global__ __launch_bounds__(256) void fill_gemm1_kernel(
        const float* __restrict__ A, const _Float16* __restrict__ BT,
        _Float16* __restrict__ C, int M,
        const int* __restrict__ erow, const int* __restrict__ ecol,
        const float* __restrict__ evals, const int* __restrict__ rptr,
        const unsigned short* __restrict__ ke, int2* __restrict__ cv, int E) {
    __shared__ __align__(16) char smem[33792];

    if (blockIdx.x >= G1_BLOCKS) {
        // ---- fill: permute (col,val) -> CSR slots, no atomics ----
        int e = (blockIdx.x - G1_BLOCKS) * 256 + threadIdx.x;
        if (e < E) {
            int p = rptr[erow[e]] + ke[e];
            cv[p] = make_int2(ecol[e], __float_as_int(evals[e]));
        }
        return;
    }

    // ---- GEMM1 (MFMA fp16): tile 64(M) x 256(N), x read once ----
    _Float16 (*As)[40]  = (_Float16 (*)[40])smem;              //  64x40  = 5120 B
    _Float16 (*Bs)[40]  = (_Float16 (*)[40])(smem + 5120);     // 256x40  = 20480 B
    _Float16 (*sC)[264] = (_Float16 (*)[264])smem;             //  64x264 = 33792 B

    const int t    = threadIdx.x;
    const int m0   = blockIdx.x * 64;
    const int lane = t & 63;
    const int wid  = t >> 6;
    const int lr   = lane & 15, lk = lane >> 4;

    f32x4 acc[4][4] = {};

    const int  ar   = t >> 2;            // 0..63
    const int  aq   = t & 3;             // 0..3
    const bool aval = (m0 + ar) < M;
    const float*    aptr = A  + (size_t)(m0 + ar) * F_IN + aq * 8;
    const _Float16* bptr = BT + (size_t)t * F_IN;              // row t of BT

    float4 a0 = {0.f,0.f,0.f,0.f}, a1 = {0.f,0.f,0.f,0.f};
    half8 b0, b1, b2, b3;
    if (aval) { a0 = *(const float4*)(aptr); a1 = *(const float4*)(aptr + 4); }
    { const half8* bp = (const half8*)(bptr); b0 = bp[0]; b1 = bp[1]; b2 = bp[2]; b3 = bp[3]; }

    for (int k0 = 0; k0 < F_IN; k0 += 32) {
        half8 ah;
        ah[0]=(_Float16)a0.x; ah[1]=(_Float16)a0.y; ah[2]=(_Float16)a0.z; ah[3]=(_Float16)a0.w;
        ah[4]=(_Float16)a1.x; ah[5]=(_Float16)a1.y; ah[6]=(_Float16)a1.z; ah[7]=(_Float16)a1.w;
        *(half8*)&As[ar][aq * 8] = ah;
        *(half8*)&Bs[t][0]  = b0;
        *(half8*)&Bs[t][8]  = b1;
        *(half8*)&Bs[t][16] = b2;
        *(half8*)&Bs[t][24] = b3;
        __syncthreads();

        if (k0 + 32 < F_IN) {
            if (aval) {
                a0 = *(const float4*)(aptr + k0 + 32);
                a1 = *(const float4*)(aptr + k0 + 36);
            }
            const half8* bp = (const half8*)(bptr + k0 + 32);
            b0 = bp[0]; b1 = bp[1]; b2 = bp[2]; b3 = bp[3];
        }

        half8 af[4], bf[4];
        #pragma unroll
        for (int fm = 0; fm < 4; fm++) af[fm] = *(half8*)&As[fm * 16 + lr][lk * 8];
        #pragma unroll
        for (int fn = 0; fn < 4; fn++) bf[fn] = *(half8*)&Bs[wid * 64 + fn * 16 + lr][lk * 8];
        #pragma unroll
        for (int fm = 0; fm < 4; fm++)
            #pragma unroll
            for (int fn = 0; fn < 4; fn++)
                acc[fm][fn] = __builtin_amdgcn_mfma_f32_16x16x32_f16(af[fm], bf[fn], acc[fm][fn], 0, 0, 0);
        __syncthreads();
    }

    #pragma unroll
    for (int fm = 0; fm < 4; fm++)
        #pragma unroll
        for (int fn = 0; fn < 4; fn++)
            #pragma unroll
            for (int j = 0; j < 4; j++) {
                int row = fm * 16 + lk * 4 + j;
                int col = wid * 64 + fn * 16 + lr;
                sC[row][col] = (_Float16)acc[fm][fn][j];
            }
    __syncthreads();

    int m = m0 + ar;
    if (m < M) {
        const float4* sp = (const float4*)&sC[ar][aq * 64];
        float4*       dp = (float4*)(C + (size_t)m * HIDDEN + aq * 64);
        #pragma unroll
        for (int j = 0; j < 8; j++) dp[j] = sp[j];
    }
}

// ---------------------------------------------------------------------------
// FUSED: SpMM gather D=256 (fp16) + ReLU + GEMM2 (@W2 via MFMA epilogue).
// 1024 threads = 16 waves = 16 rows; rows staged in LDS; one barrier;
// wave 0 computes H2[16 rows][48] with 24 MFMAs (no pad rows).
// ---------------------------------------------------------------------------
__global__ __launch_bounds__(1024) void spmm_gemm2_kernel(const int* __restrict__ rptr,
                                                          const int2* __restrict__ cv,
                                                          const _Float16* __restrict__ H1,
                                                          const _Float16* __restrict__ W2T,
                                                          _Float16* __restrict__ H2) {
    __shared__ _Float16 sW2[NPAD][264];     // 25344 B
    __shared__ _Float16 sRow[16][264];      //  8448 B

    int t = threadIdx.x;
    int wave = t >> 6, lane = t & 63;
    int m0 = blockIdx.x * FB_ROWS;
    int r = m0 + wave;

    // stage W2T (48x256 = 1536 half8 chunks) : 1.5 per thread
    #pragma unroll
    for (int i = 0; i < 2; i++) {
        int idx = t + i * 1024;             // 0..2047
        if (idx < NPAD * 32) {
            int row = idx >> 5, c8 = idx & 31;
            *(half8*)&sW2[row][c8 * 8] = *(const half8*)(W2T + (size_t)row * HIDDEN + c8 * 8);
        }
    }

    // gather: 2 edges per instr (32 lanes x 16B cover one 512B row), 8 edges/iter
    int e0 = rptr[r], e1 = rptr[r + 1];
    int hf = lane >> 5;
    int fl = lane & 31;

    float acc[8] = {};
    for (int e = e0; e < e1; e += 8) {
        #pragma unroll
        for (int u = 0; u < 4; u++) {
            int idx = e + 2 * u + hf;
            bool ok = idx < e1;
            int2 p = cv[ok ? idx : e0];
            float v = ok ? __int_as_float(p.y) : 0.f;
            half8 h = *(const half8*)(H1 + (size_t)p.x * HIDDEN + fl * 8);
            #pragma unroll
            for (int j = 0; j < 8; j++)
                acc[j] += v * (float)h[j];
        }
    }
    #pragma unroll
    for (int j = 0; j < 8; j++)
        acc[j] += __shfl_xor(acc[j], 32);

    if (hf == 0) {
        half8 o;
        #pragma unroll
        for (int j = 0; j < 8; j++) o[j] = (_Float16)fmaxf(acc[j], 0.f);
        *(half8*)&sRow[wave][fl * 8] = o;
    }
    __syncthreads();

    // MFMA epilogue on wave 0: [16x256] @ [48x256]^T  (all 16 rows real)
    if (wave == 0) {
        int lr = lane & 15, lk = lane >> 4;
        f32x4 acc2[3] = {};
        #pragma unroll
        for (int ks = 0; ks < 8; ks++) {
            half8 af = *(half8*)&sRow[lr][ks * 32 + lk * 8];
            #pragma unroll
            for (int fn = 0; fn < 3; fn++) {
                half8 bf = *(half8*)&sW2[fn * 16 + lr][ks * 32 + lk * 8];
                acc2[fn] = __builtin_amdgcn_mfma_f32_16x16x32_f16(af, bf, acc2[fn], 0, 0, 0);
            }
        }
        #pragma unroll
        for (int fn = 0; fn < 3; fn++)
            #pragma unroll
            for (int j = 0; j < 4; j++) {
                int row = lk * 4 + j;       // 0..15
                int col = fn * 16 + lr;     // 0..47
                H2[(size_t)(m0 + row) * H2STRIDE + col] = (_Float16)acc2[fn][j];
            }
    }
}

// ---------------------------------------------------------------------------
// SpMM gather D=40 (fp16, stride-64 rows = one 128B line/edge) + ReLU +
// log_softmax. One wave per row; 24 edges/iter (2 independent loads in flight).
// ---------------------------------------------------------------------------
__global__ __launch_bounds__(256) void spmm40_ls_kernel(const int* __restrict__ rptr,
                                                        const int2* __restrict__ cv,
                                                        const _Float16* __restrict__ H2,
                                                        float* __restrict__ out) {
    int t = threadIdx.x;
    int wave = t >> 6, lane = t & 63;
    int r = blockIdx.x * 4 + wave;

    int e0 = rptr[r], e1 = rptr[r + 1];
    int s = lane / 5;           // edge slot 0..11 (lane 60..63 -> s=12, inactive)
    int g = lane % 5;           // feature block: classes g*8 .. g*8+7
    bool lact = lane < 60;

    float acc[8] = {};
    for (int e = e0; e < e1; e += 24) {
        int idx0 = e + s, idx1 = e + 12 + s;
        bool ok0 = lact && (idx0 < e1);
        bool ok1 = lact && (idx1 < e1);
        int2 p0 = cv[ok0 ? idx0 : e0];
        int2 p1 = cv[ok1 ? idx1 : e0];
        float v0 = ok0 ? __int_as_float(p0.y) : 0.f;
        float v1 = ok1 ? __int_as_float(p1.y) : 0.f;
        half8 h0 = *(const half8*)(H2 + (size_t)p0.x * H2STRIDE + g * 8);
        half8 h1 = *(const half8*)(H2 + (size_t)p1.x * H2STRIDE + g * 8);
        #pragma unroll
        for (int j = 0; j < 8; j++)
            acc[j] += v0 * (float)h0[j] + v1 * (float)h1[j];
    }

    // slot-tree reduce: 12 -> 6 -> 3 -> 1 (data lives at lanes 5*s+g)
    #pragma unroll
    for (int j = 0; j < 8; j++) acc[j] += __shfl(acc[j], lane + 30);  // s<6 valid
    #pragma unroll
    for (int j = 0; j < 8; j++) acc[j] += __shfl(acc[j], lane + 15);  // s<3 valid
    #pragma unroll
    for (int j = 0; j < 8; j++) {
        float t1 = __shfl(acc[j], lane + 5);
        float t2 = __shfl(acc[j], lane + 10);
        acc[j] += t1 + t2;                                            // s==0 valid
    }

    // lanes 0..4 hold the 40 aggregated values (8 each); softmax via 8-lane tree
    bool act = lane < 5;
    float z[8];
    float mx = -INFINITY;
    #pragma unroll
    for (int j = 0; j < 8; j++) {
        z[j] = act ? fmaxf(acc[j], 0.f) : -INFINITY;
        mx = fmaxf(mx, z[j]);
    }
    mx = fmaxf(mx, __shfl_xor(mx, 1));
    mx = fmaxf(mx, __shfl_xor(mx, 2));
    mx = fmaxf(mx, __shfl_xor(mx, 4));

    float sm = 0.f;
    #pragma unroll
    for (int j = 0; j < 8; j++)
        sm += act ? expf(z[j] - mx) : 0.f;
    sm += __shfl_xor(sm, 1);
    sm += __shfl_xor(sm, 2);
    sm += __shfl_xor(sm, 4);

    float lse = logf(sm);
    if (act) {
        float4 o0 = {z[0]-mx-lse, z[1]-mx-lse, z[2]-mx-lse, z[3]-mx-lse};
        float4 o1 = {z[4]-mx-lse, z[5]-mx-lse, z[6]-mx-lse, z[7]-mx-lse};
        float4* dp = (float4*)(out + (size_t)r * NCLASS + g * 8);
        dp[0] = o0;
        dp[1] = o1;
    }
}

// ---------------------------------------------------------------------------
extern "C" void kernel_launch(void* const* d_in, const int* in_sizes, int n_in,
                              void* d_out, int out_size, void* d_ws, size_t ws_size,
                              hipStream_t stream) {
    const float* x     = (const float*)d_in[0];
    const int*   erow  = (const int*)d_in[1];
    const int*   ecol  = (const int*)d_in[2];
    const float* evals = (const float*)d_in[3];
    const float* W1    = (const float*)d_in[4];
    const float* W2    = (const float*)d_in[5];
    float* out = (float*)d_out;

    const int M = N_NODES;
    const int E = N_EDGES;

    char* p = (char*)d_ws;
    auto alloc = [&](size_t bytes) {
        char* q = p;
        p += (bytes + 255) & ~(size_t)255;
        return q;
    };
    int*            deg  = (int*)alloc(sizeof(int) * N_NODES);
    int*            rptr = (int*)alloc(sizeof(int) * (N_NODES + 1));
    int*            bsum = (int*)alloc(sizeof(int) * 512);
    unsigned short* ke   = (unsigned short*)alloc(sizeof(unsigned short) * N_EDGES); // 6.4 MB
    int2*           cv   = (int2*)alloc(sizeof(int2) * N_EDGES);                     // 25.6 MB
    _Float16*       W1T  = (_Float16*)alloc(sizeof(_Float16) * F_IN * HIDDEN);
    _Float16*       W2T  = (_Float16*)alloc(sizeof(_Float16) * NPAD * HIDDEN);
    _Float16*       H1   = (_Float16*)alloc(sizeof(_Float16) * (size_t)N_NODES * HIDDEN);   // 51.2 MB
    _Float16*       H2   = (_Float16*)alloc(sizeof(_Float16) * (size_t)N_NODES * H2STRIDE); // 12.8 MB

    // K1: deg=0 + weight conversions
    init_kernel<<<(F_IN * HIDDEN) / 256, 256, 0, stream>>>(W1, W2, W1T, W2T, deg);

    // K2: histogram + per-edge rank
    hist2_kernel<<<E / 256, 256, 0, stream>>>(erow, deg, ke, E);

    // K3-K5: exclusive scan of deg -> rptr
    scanA_kernel<<<N_SCANB, SCAN_B, 0, stream>>>(deg, rptr, bsum, N_NODES);
    scanB_kernel<<<1, 512, 0, stream>>>(bsum, N_SCANB);
    scanC_kernel<<<N_SCANB, SCAN_B, 0, stream>>>(rptr, bsum, N_NODES, E);

    // K6: merged GEMM1 (blocks 0..1562)  ||  CSR fill (blocks 1563..14062)
    fill_gemm1_kernel<<<G1_BLOCKS + FILL_BLOCKS, 256, 0, stream>>>(
        x, W1T, H1, M, erow, ecol, evals, rptr, ke, cv, E);

    // K7: fused layer-1 aggregation + relu + @W2 (MFMA epilogue), 16 rows/block
    spmm_gemm2_kernel<<<M / FB_ROWS, 1024, 0, stream>>>(rptr, cv, H1, W2T, H2);

    // K8: layer-2 aggregation + relu + log_softmax
    spmm40_ls_kernel<<<M / 4, 256, 0, stream>>>(rptr, cv, H2, out);
}